// Round 1
// baseline (1940.013 us; speedup 1.0000x reference)
//
#include <hip/hip_runtime.h>
#include <hip/hip_bf16.h>

#define N_NODES 100000
#define N_EDGES 1600000
#define IN_F    128
#define N_HID   512
#define N_CLS   64
#define BN_EPS  1e-5f

typedef __hip_bfloat16 bf16;

// ---------------- CSR build ----------------
__global__ void count_k(const int* __restrict__ dst, int* __restrict__ counts) {
    int e = blockIdx.x * 256 + threadIdx.x;
    if (e < N_EDGES) atomicAdd(&counts[dst[e]], 1);
}

// single block, 1024 threads, 4 elements/thread/iter. counts -> cursor(start), indptr
__global__ void __launch_bounds__(1024) scan_k(int* __restrict__ counts, int* __restrict__ indptr) {
    __shared__ int buf[1024];
    __shared__ int s_carry;
    int tid = threadIdx.x;
    if (tid == 0) { s_carry = 0; indptr[0] = 0; }
    __syncthreads();
    for (int base = 0; base < N_NODES; base += 4096) {
        int idx = base + tid * 4;
        int4 v = *(const int4*)(counts + idx);   // padded region is zeroed
        int s = v.x + v.y + v.z + v.w;
        buf[tid] = s;
        __syncthreads();
        for (int off = 1; off < 1024; off <<= 1) {
            int t = (tid >= off) ? buf[tid - off] : 0;
            __syncthreads();
            buf[tid] += t;
            __syncthreads();
        }
        int incl  = buf[tid];
        int total = buf[1023];
        int c = s_carry;
        __syncthreads();
        int p = c + incl - s;            // exclusive prefix for element idx
        int4 cur;
        cur.x = p;
        cur.y = p + v.x;
        cur.z = p + v.x + v.y;
        cur.w = p + v.x + v.y + v.z;
        *(int4*)(counts + idx) = cur;    // counts becomes cursor (start offsets)
        indptr[idx + 1] = cur.y;
        indptr[idx + 2] = cur.z;
        indptr[idx + 3] = cur.w;
        indptr[idx + 4] = p + s;
        if (tid == 0) s_carry = c + total;
        __syncthreads();
    }
}

__global__ void scatter_k(const int* __restrict__ src, const int* __restrict__ dst,
                          const float* __restrict__ norm, int* __restrict__ cursor,
                          int* __restrict__ ssrc, float* __restrict__ snorm) {
    int e = blockIdx.x * 256 + threadIdx.x;
    if (e < N_EDGES) {
        int pos = atomicAdd(&cursor[dst[e]], 1);
        ssrc[pos]  = src[e];
        snorm[pos] = norm[e];
    }
}

// ---------------- propagation hop: one node per 128-thread block ----------------
__global__ void __launch_bounds__(128) hop_k(const float* __restrict__ fin, float* __restrict__ fout,
                                             const int* __restrict__ indptr,
                                             const int* __restrict__ ssrc,
                                             const float* __restrict__ snorm) {
    int n = blockIdx.x;
    int t = threadIdx.x;
    int beg = indptr[n], end = indptr[n + 1];
    float acc = 0.f;
    for (int e = beg; e < end; e++) {
        int   s = ssrc[e];
        float w = snorm[e];
        acc += fin[(size_t)s * IN_F + t] * w;
    }
    fout[(size_t)n * IN_F + t] = acc;
}

// ---------------- Gram matrix G = ft^T ft (128x128) + column sums ----------------
#define GR_CHUNK 256
__global__ void __launch_bounds__(256) gram_k(const float* __restrict__ ft,
                                              float* __restrict__ G,
                                              float* __restrict__ colsum) {
    __shared__ float sF[32][128];
    int tid = threadIdx.x;
    int tx = tid & 15, ty = tid >> 4;
    float acc[8][8];
#pragma unroll
    for (int i = 0; i < 8; i++)
#pragma unroll
        for (int j = 0; j < 8; j++) acc[i][j] = 0.f;
    float cs[8] = {0.f,0.f,0.f,0.f,0.f,0.f,0.f,0.f};
    int row0 = blockIdx.x * GR_CHUNK;
    for (int rb = 0; rb < GR_CHUNK; rb += 32) {
        __syncthreads();
        for (int i = tid; i < 32 * 128; i += 256) {
            int r = row0 + rb + (i >> 7);
            sF[i >> 7][i & 127] = (r < N_NODES) ? ft[(size_t)r * IN_F + (i & 127)] : 0.f;
        }
        __syncthreads();
        for (int r = 0; r < 32; r++) {
            float a[8], b[8];
#pragma unroll
            for (int i = 0; i < 8; i++) a[i] = sF[r][ty * 8 + i];
#pragma unroll
            for (int j = 0; j < 8; j++) b[j] = sF[r][tx * 8 + j];
#pragma unroll
            for (int i = 0; i < 8; i++)
#pragma unroll
                for (int j = 0; j < 8; j++) acc[i][j] += a[i] * b[j];
            if (ty == 0) {
#pragma unroll
                for (int j = 0; j < 8; j++) cs[j] += b[j];
            }
        }
    }
#pragma unroll
    for (int i = 0; i < 8; i++)
#pragma unroll
        for (int j = 0; j < 8; j++)
            atomicAdd(&G[(ty * 8 + i) * 128 + tx * 8 + j], acc[i][j]);
    if (ty == 0) {
#pragma unroll
        for (int j = 0; j < 8; j++) atomicAdd(&colsum[tx * 8 + j], cs[j]);
    }
}

// ---------------- BN stats from Gram: scale/shift per hidden unit ----------------
__global__ void __launch_bounds__(64) bnstat_k(const float* __restrict__ G,
                                               const float* __restrict__ colsum,
                                               const float* __restrict__ W1,
                                               const float* __restrict__ b1,
                                               const float* __restrict__ gamma,
                                               const float* __restrict__ beta,
                                               float* __restrict__ scale,
                                               float* __restrict__ shift) {
    __shared__ float sW[64][129];
    int tid = threadIdx.x;
    int j = blockIdx.x * 64 + tid;
    for (int i = tid; i < 64 * 128; i += 64)
        sW[i >> 7][i & 127] = W1[(size_t)blockIdx.x * 64 * IN_F + i];
    __syncthreads();
    const float* wrow = sW[tid];
    float m = 0.f, q = 0.f;
    for (int k = 0; k < 128; k++) {
        float wk = wrow[k];
        m += colsum[k] * wk;
        float t = 0.f;
#pragma unroll 4
        for (int l = 0; l < 128; l++) t += G[k * 128 + l] * wrow[l];
        q += wk * t;
    }
    const float invN = 1.f / (float)N_NODES;
    float mean_dot = m * invN;
    float var = q * invN - mean_dot * mean_dot;
    float inv = rsqrtf(var + BN_EPS);
    float s = gamma[j] * inv;
    scale[j] = s;
    shift[j] = beta[j] - (mean_dot + b1[j]) * s;
}

// ---------------- fused fc1 -> BN -> ReLU -> fc2 ----------------
__global__ void __launch_bounds__(256) mlp_k(const float* __restrict__ ft,
                                             const float* __restrict__ W1,
                                             const float* __restrict__ b1,
                                             const float* __restrict__ scale,
                                             const float* __restrict__ shift,
                                             const float* __restrict__ W2,
                                             const float* __restrict__ b2,
                                             float* __restrict__ out) {
    __shared__ bf16 sF[64][128];     // 16.0 KB  node-rows x in_feats
    __shared__ bf16 sW1t[128][66];   // 16.9 KB  [k][j]  (transposed, padded)
    __shared__ bf16 sH[64][66];      //  8.4 KB  relu(bn(h)) chunk
    __shared__ bf16 sW2t[64][66];    //  8.4 KB  [k][c]
    int tid = threadIdx.x;
    int tx = tid & 15, ty = tid >> 4;
    int row0 = blockIdx.x * 64;

    for (int i = tid; i < 64 * 128; i += 256) {
        int r = row0 + (i >> 7);
        float v = (r < N_NODES) ? ft[(size_t)r * IN_F + (i & 127)] : 0.f;
        sF[i >> 7][i & 127] = __float2bfloat16(v);
    }

    float oacc[4][4];
#pragma unroll
    for (int i = 0; i < 4; i++)
#pragma unroll
        for (int j = 0; j < 4; j++) oacc[i][j] = 0.f;

    for (int jc = 0; jc < 8; jc++) {
        int j0 = jc * 64;
        __syncthreads();
        for (int i = tid; i < 64 * 128; i += 256) {
            int j = i >> 7, k = i & 127;
            sW1t[k][j] = __float2bfloat16(W1[(size_t)(j0 + j) * IN_F + k]);
        }
        for (int i = tid; i < 64 * 64; i += 256) {
            int c = i >> 6, k = i & 63;
            sW2t[k][c] = __float2bfloat16(W2[(size_t)c * N_HID + j0 + k]);
        }
        __syncthreads();

        float h[4][4];
#pragma unroll
        for (int i = 0; i < 4; i++)
#pragma unroll
            for (int j = 0; j < 4; j++) h[i][j] = 0.f;
#pragma unroll 8
        for (int k = 0; k < 128; k++) {
            float a[4], b[4];
#pragma unroll
            for (int i = 0; i < 4; i++) a[i] = __bfloat162float(sF[ty * 4 + i][k]);
#pragma unroll
            for (int j = 0; j < 4; j++) b[j] = __bfloat162float(sW1t[k][tx * 4 + j]);
#pragma unroll
            for (int i = 0; i < 4; i++)
#pragma unroll
                for (int j = 0; j < 4; j++) h[i][j] += a[i] * b[j];
        }
#pragma unroll
        for (int j = 0; j < 4; j++) {
            int col = j0 + tx * 4 + j;
            float sc = scale[col], sh = shift[col], bb = b1[col];
#pragma unroll
            for (int i = 0; i < 4; i++) {
                float v = (h[i][j] + bb) * sc + sh;
                sH[ty * 4 + i][tx * 4 + j] = __float2bfloat16(fmaxf(v, 0.f));
            }
        }
        __syncthreads();
#pragma unroll 8
        for (int k = 0; k < 64; k++) {
            float a[4], b[4];
#pragma unroll
            for (int i = 0; i < 4; i++) a[i] = __bfloat162float(sH[ty * 4 + i][k]);
#pragma unroll
            for (int j = 0; j < 4; j++) b[j] = __bfloat162float(sW2t[k][tx * 4 + j]);
#pragma unroll
            for (int i = 0; i < 4; i++)
#pragma unroll
                for (int j = 0; j < 4; j++) oacc[i][j] += a[i] * b[j];
        }
    }
#pragma unroll
    for (int i = 0; i < 4; i++) {
        int r = row0 + ty * 4 + i;
        if (r < N_NODES) {
#pragma unroll
            for (int j = 0; j < 4; j++)
                out[(size_t)r * N_CLS + tx * 4 + j] = oacc[i][j] + b2[tx * 4 + j];
        }
    }
}

extern "C" void kernel_launch(void* const* d_in, const int* in_sizes, int n_in,
                              void* d_out, int out_size, void* d_ws, size_t ws_size,
                              hipStream_t stream) {
    const float* feat  = (const float*)d_in[0];
    const int*   src   = (const int*)d_in[1];
    const int*   dst   = (const int*)d_in[2];
    const float* gnorm = (const float*)d_in[3];
    const float* fc1w  = (const float*)d_in[4];
    const float* fc1b  = (const float*)d_in[5];
    const float* gam   = (const float*)d_in[6];
    const float* bet   = (const float*)d_in[7];
    const float* fc2w  = (const float*)d_in[8];
    const float* fc2b  = (const float*)d_in[9];
    float* out = (float*)d_out;

    char* ws = (char*)d_ws;
    const size_t FT_BYTES = (size_t)N_NODES * IN_F * 4;       // 51,200,000
    size_t off = 0;
    float* ftA    = (float*)(ws + off); off += FT_BYTES;
    float* ftB    = (float*)(ws + off); off += FT_BYTES;
    int*   indptr = (int*)(ws + off);   off += 410112;        // 102,528 ints (padded)
    int*   cursor = (int*)(ws + off);   off += 409600;        // 102,400 ints (padded)
    int*   ssrc   = (int*)(ws + off);   off += (size_t)N_EDGES * 4;
    float* snorm  = (float*)(ws + off); off += (size_t)N_EDGES * 4;
    float* G      = (float*)(ws + off); off += 128 * 128 * 4;
    float* colsum = (float*)(ws + off); off += 512;
    float* scale  = (float*)(ws + off); off += 2048;
    float* shift  = (float*)(ws + off); off += 2048;
    (void)ws_size; (void)in_sizes; (void)n_in; (void)out_size;

    // zero: counts/cursor (incl. padding), Gram + colsum (contiguous)
    hipMemsetAsync(cursor, 0, 409600, stream);
    hipMemsetAsync(G, 0, 128 * 128 * 4 + 512, stream);

    // CSR build
    count_k<<<N_EDGES / 256, 256, 0, stream>>>(dst, cursor);
    scan_k<<<1, 1024, 0, stream>>>(cursor, indptr);
    scatter_k<<<N_EDGES / 256, 256, 0, stream>>>(src, dst, gnorm, cursor, ssrc, snorm);

    // 3 propagation hops: feat -> ftA -> ftB -> ftA
    hop_k<<<N_NODES, 128, 0, stream>>>(feat, ftA, indptr, ssrc, snorm);
    hop_k<<<N_NODES, 128, 0, stream>>>(ftA, ftB, indptr, ssrc, snorm);
    hop_k<<<N_NODES, 128, 0, stream>>>(ftB, ftA, indptr, ssrc, snorm);

    // BN stats via Gram matrix
    gram_k<<<(N_NODES + GR_CHUNK - 1) / GR_CHUNK, 256, 0, stream>>>(ftA, G, colsum);
    bnstat_k<<<N_HID / 64, 64, 0, stream>>>(G, colsum, fc1w, fc1b, gam, bet, scale, shift);

    // fused MLP
    mlp_k<<<(N_NODES + 63) / 64, 256, 0, stream>>>(ftA, fc1w, fc1b, scale, shift,
                                                   fc2w, fc2b, out);
}

// Round 2
// 1433.900 us; speedup vs baseline: 1.3530x; 1.3530x over previous
//
#include <hip/hip_runtime.h>
#include <hip/hip_bf16.h>

#define N_NODES 100000
#define N_EDGES 1600000
#define IN_F    128
#define N_HID   512
#define N_CLS   64
#define BN_EPS  1e-5f

typedef __attribute__((ext_vector_type(8))) short short8;
typedef __attribute__((ext_vector_type(4))) float floatx4;

__device__ __forceinline__ short f2bf(float x) {
    union { float f; unsigned u; } t; t.f = x;
    unsigned r = (t.u + 0x7fffu + ((t.u >> 16) & 1u)) >> 16;
    return (short)r;
}

// ---------------- CSR build ----------------
__global__ void count_k(const int* __restrict__ dst, int* __restrict__ counts) {
    int e = blockIdx.x * 256 + threadIdx.x;
    if (e < N_EDGES) atomicAdd(&counts[dst[e]], 1);
}

__global__ void __launch_bounds__(1024) scan_k(int* __restrict__ counts, int* __restrict__ indptr) {
    __shared__ int buf[1024];
    __shared__ int s_carry;
    int tid = threadIdx.x;
    if (tid == 0) { s_carry = 0; indptr[0] = 0; }
    __syncthreads();
    for (int base = 0; base < N_NODES; base += 4096) {
        int idx = base + tid * 4;
        int4 v = *(const int4*)(counts + idx);
        int s = v.x + v.y + v.z + v.w;
        buf[tid] = s;
        __syncthreads();
        for (int off = 1; off < 1024; off <<= 1) {
            int t = (tid >= off) ? buf[tid - off] : 0;
            __syncthreads();
            buf[tid] += t;
            __syncthreads();
        }
        int incl  = buf[tid];
        int total = buf[1023];
        int c = s_carry;
        __syncthreads();
        int p = c + incl - s;
        int4 cur;
        cur.x = p;
        cur.y = p + v.x;
        cur.z = p + v.x + v.y;
        cur.w = p + v.x + v.y + v.z;
        *(int4*)(counts + idx) = cur;
        indptr[idx + 1] = cur.y;
        indptr[idx + 2] = cur.z;
        indptr[idx + 3] = cur.w;
        indptr[idx + 4] = p + s;
        if (tid == 0) s_carry = c + total;
        __syncthreads();
    }
}

__global__ void scatter_k(const int* __restrict__ src, const int* __restrict__ dst,
                          const float* __restrict__ norm, int* __restrict__ cursor,
                          int* __restrict__ ssrc, float* __restrict__ snorm) {
    int e = blockIdx.x * 256 + threadIdx.x;
    if (e < N_EDGES) {
        int pos = atomicAdd(&cursor[dst[e]], 1);
        ssrc[pos]  = src[e];
        snorm[pos] = norm[e];
    }
}

// ---------------- propagation hop: one node per wave, float4, 2 edges in flight --
__global__ void __launch_bounds__(256) hop_k(const float4* __restrict__ fin,
                                             float4* __restrict__ fout,
                                             const int* __restrict__ indptr,
                                             const int* __restrict__ ssrc,
                                             const float* __restrict__ snorm) {
    int node = blockIdx.x * 4 + (threadIdx.x >> 6);
    if (node >= N_NODES) return;
    int l    = threadIdx.x & 63;
    int half = l >> 5;          // which edge of the in-flight pair
    int c4   = l & 31;          // float4 index within the 128-float row
    int beg = indptr[node], end = indptr[node + 1];
    float4 acc = {0.f, 0.f, 0.f, 0.f};
#pragma unroll 2
    for (int e = beg + half; e < end; e += 2) {
        int   s  = ssrc[e];
        float wt = snorm[e];
        float4 v = fin[(size_t)s * 32 + c4];
        acc.x += v.x * wt; acc.y += v.y * wt;
        acc.z += v.z * wt; acc.w += v.w * wt;
    }
    acc.x += __shfl_xor(acc.x, 32, 64);
    acc.y += __shfl_xor(acc.y, 32, 64);
    acc.z += __shfl_xor(acc.z, 32, 64);
    acc.w += __shfl_xor(acc.w, 32, 64);
    if (half == 0) fout[(size_t)node * 32 + c4] = acc;
}

// ---------------- Gram matrix G = ft^T ft (128x128) + column sums ----------------
#define GR_CHUNK 256
__global__ void __launch_bounds__(256) gram_k(const float* __restrict__ ft,
                                              float* __restrict__ G,
                                              float* __restrict__ colsum) {
    __shared__ float sF[32][128];
    int tid = threadIdx.x;
    int tx = tid & 15, ty = tid >> 4;
    float acc[8][8];
#pragma unroll
    for (int i = 0; i < 8; i++)
#pragma unroll
        for (int j = 0; j < 8; j++) acc[i][j] = 0.f;
    float cs[8] = {0.f,0.f,0.f,0.f,0.f,0.f,0.f,0.f};
    int row0 = blockIdx.x * GR_CHUNK;
    for (int rb = 0; rb < GR_CHUNK; rb += 32) {
        __syncthreads();
        for (int i = tid; i < 32 * 128; i += 256) {
            int r = row0 + rb + (i >> 7);
            sF[i >> 7][i & 127] = (r < N_NODES) ? ft[(size_t)r * IN_F + (i & 127)] : 0.f;
        }
        __syncthreads();
        for (int r = 0; r < 32; r++) {
            float a[8], b[8];
#pragma unroll
            for (int i = 0; i < 8; i++) a[i] = sF[r][ty * 8 + i];
#pragma unroll
            for (int j = 0; j < 8; j++) b[j] = sF[r][tx * 8 + j];
#pragma unroll
            for (int i = 0; i < 8; i++)
#pragma unroll
                for (int j = 0; j < 8; j++) acc[i][j] += a[i] * b[j];
            if (ty == 0) {
#pragma unroll
                for (int j = 0; j < 8; j++) cs[j] += b[j];
            }
        }
    }
#pragma unroll
    for (int i = 0; i < 8; i++)
#pragma unroll
        for (int j = 0; j < 8; j++)
            atomicAdd(&G[(ty * 8 + i) * 128 + tx * 8 + j], acc[i][j]);
    if (ty == 0) {
#pragma unroll
        for (int j = 0; j < 8; j++) atomicAdd(&colsum[tx * 8 + j], cs[j]);
    }
}

// ---------------- BN stats from Gram ----------------
__global__ void __launch_bounds__(64) bnstat_k(const float* __restrict__ G,
                                               const float* __restrict__ colsum,
                                               const float* __restrict__ W1,
                                               const float* __restrict__ b1,
                                               const float* __restrict__ gamma,
                                               const float* __restrict__ beta,
                                               float* __restrict__ scale,
                                               float* __restrict__ shift) {
    __shared__ float sW[64][129];
    int tid = threadIdx.x;
    int j = blockIdx.x * 64 + tid;
    for (int i = tid; i < 64 * 128; i += 64)
        sW[i >> 7][i & 127] = W1[(size_t)blockIdx.x * 64 * IN_F + i];
    __syncthreads();
    const float* wrow = sW[tid];
    float m = 0.f, q = 0.f;
    for (int k = 0; k < 128; k++) {
        float wk = wrow[k];
        m += colsum[k] * wk;
        float t = 0.f;
#pragma unroll 4
        for (int l = 0; l < 128; l++) t += G[k * 128 + l] * wrow[l];
        q += wk * t;
    }
    const float invN = 1.f / (float)N_NODES;
    float mean_dot = m * invN;
    float var = q * invN - mean_dot * mean_dot;
    float inv = rsqrtf(var + BN_EPS);
    float s = gamma[j] * inv;
    scale[j] = s;
    shift[j] = beta[j] - (mean_dot + b1[j]) * s;
}

// ---------------- weight bf16 pre-conversion ----------------
__global__ void cvtw_k(const float* __restrict__ w1, const float* __restrict__ w2,
                       short* __restrict__ w1b, short* __restrict__ w2b) {
    int i = blockIdx.x * 256 + threadIdx.x;
    if (i < N_HID * IN_F) w1b[i] = f2bf(w1[i]);
    if (i < N_CLS * N_HID) w2b[i] = f2bf(w2[i]);
}

// ---------------- fused fc1 -> BN -> ReLU -> fc2, MFMA ----------------
// block = 128 node-rows, 4 waves; wave = 32-row stripe x 64-col tiles (2x4 frags)
__global__ void __launch_bounds__(256) mlp_k(const float* __restrict__ ft,
                                             const short* __restrict__ w1b,
                                             const float* __restrict__ b1,
                                             const float* __restrict__ scale,
                                             const float* __restrict__ shift,
                                             const short* __restrict__ w2b,
                                             const float* __restrict__ b2,
                                             float* __restrict__ out) {
    __shared__ short sA[128][136];   // 34.8 KB  bf16 ft rows (pad +8 shorts)
    __shared__ short sW1[64][136];   // 17.4 KB  W1 chunk [hid][k]
    __shared__ short sH[128][72];    // 18.4 KB  relu(bn(h)) chunk [row][j]
    __shared__ short sW2[64][72];    //  9.2 KB  W2 chunk [cls][k]

    int tid = threadIdx.x;
    int w   = tid >> 6;        // wave 0..3 -> 32-row stripe
    int l   = tid & 63;
    int q   = l >> 4;          // quad 0..3
    int r16 = l & 15;
    int row0 = blockIdx.x * 128;

    // stage ft rows -> bf16 LDS
    const float4* ft4 = (const float4*)ft;
    for (int i = tid; i < 128 * 32; i += 256) {
        int r = i >> 5, c = i & 31;
        int gr = row0 + r;
        float4 v = {0.f, 0.f, 0.f, 0.f};
        if (gr < N_NODES) v = ft4[(size_t)gr * 32 + c];
        sA[r][c * 4 + 0] = f2bf(v.x);
        sA[r][c * 4 + 1] = f2bf(v.y);
        sA[r][c * 4 + 2] = f2bf(v.z);
        sA[r][c * 4 + 3] = f2bf(v.w);
    }

    floatx4 oacc[2][4];
#pragma unroll
    for (int rt = 0; rt < 2; rt++)
#pragma unroll
        for (int tc = 0; tc < 4; tc++) oacc[rt][tc] = (floatx4){0.f, 0.f, 0.f, 0.f};

    for (int jc = 0; jc < 8; jc++) {
        int j0 = jc * 64;
        __syncthreads();
        // stage W1 chunk [64][128] and W2 chunk [64][64] (bf16, wide loads)
        for (int i = tid; i < 64 * 16; i += 256) {
            int j = i >> 4, k8 = i & 15;
            *(int4*)&sW1[j][k8 * 8] = *(const int4*)&w1b[(size_t)(j0 + j) * IN_F + k8 * 8];
        }
        for (int i = tid; i < 64 * 8; i += 256) {
            int c = i >> 3, k8 = i & 7;
            *(int4*)&sW2[c][k8 * 8] = *(const int4*)&w2b[(size_t)c * N_HID + j0 + k8 * 8];
        }
        __syncthreads();

        // fc1: h[32 x 64] per wave
        floatx4 hacc[2][4];
#pragma unroll
        for (int rt = 0; rt < 2; rt++)
#pragma unroll
            for (int tn = 0; tn < 4; tn++) hacc[rt][tn] = (floatx4){0.f, 0.f, 0.f, 0.f};
#pragma unroll
        for (int ks = 0; ks < 4; ks++) {
            short8 a0 = *(const short8*)&sA[w * 32 + r16][ks * 32 + q * 8];
            short8 a1 = *(const short8*)&sA[w * 32 + 16 + r16][ks * 32 + q * 8];
#pragma unroll
            for (int tn = 0; tn < 4; tn++) {
                short8 b = *(const short8*)&sW1[tn * 16 + r16][ks * 32 + q * 8];
                hacc[0][tn] = __builtin_amdgcn_mfma_f32_16x16x32_bf16(a0, b, hacc[0][tn], 0, 0, 0);
                hacc[1][tn] = __builtin_amdgcn_mfma_f32_16x16x32_bf16(a1, b, hacc[1][tn], 0, 0, 0);
            }
        }
        // BN + ReLU, C-layout -> sH (A-layout source for fc2)
#pragma unroll
        for (int tn = 0; tn < 4; tn++) {
            int col = j0 + tn * 16 + r16;
            float sc = scale[col], sh = shift[col], bb = b1[col];
#pragma unroll
            for (int rt = 0; rt < 2; rt++)
#pragma unroll
                for (int i = 0; i < 4; i++) {
                    float v = (hacc[rt][tn][i] + bb) * sc + sh;
                    sH[w * 32 + rt * 16 + q * 4 + i][tn * 16 + r16] = f2bf(fmaxf(v, 0.f));
                }
        }
        __syncthreads();
        // fc2 partial: oacc += h_chunk @ W2_chunk^T
#pragma unroll
        for (int ks = 0; ks < 2; ks++) {
            short8 a0 = *(const short8*)&sH[w * 32 + r16][ks * 32 + q * 8];
            short8 a1 = *(const short8*)&sH[w * 32 + 16 + r16][ks * 32 + q * 8];
#pragma unroll
            for (int tc = 0; tc < 4; tc++) {
                short8 b = *(const short8*)&sW2[tc * 16 + r16][ks * 32 + q * 8];
                oacc[0][tc] = __builtin_amdgcn_mfma_f32_16x16x32_bf16(a0, b, oacc[0][tc], 0, 0, 0);
                oacc[1][tc] = __builtin_amdgcn_mfma_f32_16x16x32_bf16(a1, b, oacc[1][tc], 0, 0, 0);
            }
        }
    }

    // epilogue
#pragma unroll
    for (int rt = 0; rt < 2; rt++)
#pragma unroll
        for (int tc = 0; tc < 4; tc++) {
            int col = tc * 16 + r16;
            float bb = b2[col];
#pragma unroll
            for (int i = 0; i < 4; i++) {
                int r = row0 + w * 32 + rt * 16 + q * 4 + i;
                if (r < N_NODES) out[(size_t)r * N_CLS + col] = oacc[rt][tc][i] + bb;
            }
        }
}

extern "C" void kernel_launch(void* const* d_in, const int* in_sizes, int n_in,
                              void* d_out, int out_size, void* d_ws, size_t ws_size,
                              hipStream_t stream) {
    const float* feat  = (const float*)d_in[0];
    const int*   src   = (const int*)d_in[1];
    const int*   dst   = (const int*)d_in[2];
    const float* gnorm = (const float*)d_in[3];
    const float* fc1w  = (const float*)d_in[4];
    const float* fc1b  = (const float*)d_in[5];
    const float* gam   = (const float*)d_in[6];
    const float* bet   = (const float*)d_in[7];
    const float* fc2w  = (const float*)d_in[8];
    const float* fc2b  = (const float*)d_in[9];
    float* out = (float*)d_out;

    char* ws = (char*)d_ws;
    const size_t FT_BYTES = (size_t)N_NODES * IN_F * 4;
    size_t off = 0;
    float* ftA    = (float*)(ws + off); off += FT_BYTES;
    float* ftB    = (float*)(ws + off); off += FT_BYTES;
    int*   indptr = (int*)(ws + off);   off += 410112;
    int*   cursor = (int*)(ws + off);   off += 409600;
    int*   ssrc   = (int*)(ws + off);   off += (size_t)N_EDGES * 4;
    float* snorm  = (float*)(ws + off); off += (size_t)N_EDGES * 4;
    float* G      = (float*)(ws + off); off += 128 * 128 * 4;
    float* colsum = (float*)(ws + off); off += 512;
    float* scale  = (float*)(ws + off); off += 2048;
    float* shift  = (float*)(ws + off); off += 2048;
    short* w1b    = (short*)(ws + off); off += (size_t)N_HID * IN_F * 2;
    short* w2b    = (short*)(ws + off); off += (size_t)N_CLS * N_HID * 2;
    (void)ws_size; (void)in_sizes; (void)n_in; (void)out_size;

    hipMemsetAsync(cursor, 0, 409600, stream);
    hipMemsetAsync(G, 0, 128 * 128 * 4 + 512, stream);

    // weight conversion (independent; overlaps CSR build)
    cvtw_k<<<(N_HID * IN_F + 255) / 256, 256, 0, stream>>>(fc1w, fc2w, w1b, w2b);

    // CSR build
    count_k<<<N_EDGES / 256, 256, 0, stream>>>(dst, cursor);
    scan_k<<<1, 1024, 0, stream>>>(cursor, indptr);
    scatter_k<<<N_EDGES / 256, 256, 0, stream>>>(src, dst, gnorm, cursor, ssrc, snorm);

    // 3 propagation hops: feat -> ftA -> ftB -> ftA
    hop_k<<<(N_NODES + 3) / 4, 256, 0, stream>>>((const float4*)feat, (float4*)ftA, indptr, ssrc, snorm);
    hop_k<<<(N_NODES + 3) / 4, 256, 0, stream>>>((const float4*)ftA, (float4*)ftB, indptr, ssrc, snorm);
    hop_k<<<(N_NODES + 3) / 4, 256, 0, stream>>>((const float4*)ftB, (float4*)ftA, indptr, ssrc, snorm);

    // BN stats via Gram matrix
    gram_k<<<(N_NODES + GR_CHUNK - 1) / GR_CHUNK, 256, 0, stream>>>(ftA, G, colsum);
    bnstat_k<<<N_HID / 64, 64, 0, stream>>>(G, colsum, fc1w, fc1b, gam, bet, scale, shift);

    // fused MFMA MLP
    mlp_k<<<(N_NODES + 127) / 128, 256, 0, stream>>>(ftA, w1b, fc1b, scale, shift,
                                                     w2b, fc2b, out);
}

// Round 3
// 1043.008 us; speedup vs baseline: 1.8600x; 1.3748x over previous
//
#include <hip/hip_runtime.h>
#include <hip/hip_bf16.h>

#define N_NODES 100000
#define N_EDGES 1600000
#define IN_F    128
#define N_HID   512
#define N_CLS   64
#define BN_EPS  1e-5f

typedef __attribute__((ext_vector_type(8))) short short8;
typedef __attribute__((ext_vector_type(4))) float floatx4;

__device__ __forceinline__ short f2bf(float x) {
    union { float f; unsigned u; } t; t.f = x;
    unsigned r = (t.u + 0x7fffu + ((t.u >> 16) & 1u)) >> 16;
    return (short)r;
}

// ---------------- CSR build ----------------
__global__ void count_k(const int* __restrict__ dst, int* __restrict__ counts) {
    int e = blockIdx.x * 256 + threadIdx.x;
    if (e < N_EDGES) atomicAdd(&counts[dst[e]], 1);
}

__global__ void __launch_bounds__(1024) scan_k(int* __restrict__ counts, int* __restrict__ indptr) {
    __shared__ int buf[1024];
    __shared__ int s_carry;
    int tid = threadIdx.x;
    if (tid == 0) { s_carry = 0; indptr[0] = 0; }
    __syncthreads();
    for (int base = 0; base < N_NODES; base += 4096) {
        int idx = base + tid * 4;
        int4 v = *(const int4*)(counts + idx);
        int s = v.x + v.y + v.z + v.w;
        buf[tid] = s;
        __syncthreads();
        for (int off = 1; off < 1024; off <<= 1) {
            int t = (tid >= off) ? buf[tid - off] : 0;
            __syncthreads();
            buf[tid] += t;
            __syncthreads();
        }
        int incl  = buf[tid];
        int total = buf[1023];
        int c = s_carry;
        __syncthreads();
        int p = c + incl - s;
        int4 cur;
        cur.x = p;
        cur.y = p + v.x;
        cur.z = p + v.x + v.y;
        cur.w = p + v.x + v.y + v.z;
        *(int4*)(counts + idx) = cur;
        indptr[idx + 1] = cur.y;
        indptr[idx + 2] = cur.z;
        indptr[idx + 3] = cur.w;
        indptr[idx + 4] = p + s;
        if (tid == 0) s_carry = c + total;
        __syncthreads();
    }
}

__global__ void scatter_k(const int* __restrict__ src, const int* __restrict__ dst,
                          const float* __restrict__ norm, int* __restrict__ cursor,
                          int* __restrict__ ssrc, float* __restrict__ snorm) {
    int e = blockIdx.x * 256 + threadIdx.x;
    if (e < N_EDGES) {
        int pos = atomicAdd(&cursor[dst[e]], 1);
        ssrc[pos]  = src[e];
        snorm[pos] = norm[e];
    }
}

// ---------------- propagation hop: one node per wave, float4, 2 edges in flight --
__global__ void __launch_bounds__(256) hop_k(const float4* __restrict__ fin,
                                             float4* __restrict__ fout,
                                             const int* __restrict__ indptr,
                                             const int* __restrict__ ssrc,
                                             const float* __restrict__ snorm) {
    int node = blockIdx.x * 4 + (threadIdx.x >> 6);
    if (node >= N_NODES) return;
    int l    = threadIdx.x & 63;
    int half = l >> 5;          // which edge of the in-flight pair
    int c4   = l & 31;          // float4 index within the 128-float row
    int beg = indptr[node], end = indptr[node + 1];
    float4 acc = {0.f, 0.f, 0.f, 0.f};
#pragma unroll 2
    for (int e = beg + half; e < end; e += 2) {
        int   s  = ssrc[e];
        float wt = snorm[e];
        float4 v = fin[(size_t)s * 32 + c4];
        acc.x += v.x * wt; acc.y += v.y * wt;
        acc.z += v.z * wt; acc.w += v.w * wt;
    }
    acc.x += __shfl_xor(acc.x, 32, 64);
    acc.y += __shfl_xor(acc.y, 32, 64);
    acc.z += __shfl_xor(acc.z, 32, 64);
    acc.w += __shfl_xor(acc.w, 32, 64);
    if (half == 0) fout[(size_t)node * 32 + c4] = acc;
}

// ---------------- Gram matrix G = ft^T ft (128x128) + column sums ----------------
#define GR_CHUNK 256
__global__ void __launch_bounds__(256) gram_k(const float* __restrict__ ft,
                                              float* __restrict__ G,
                                              float* __restrict__ colsum) {
    __shared__ float sF[32][128];
    int tid = threadIdx.x;
    int tx = tid & 15, ty = tid >> 4;
    float acc[8][8];
#pragma unroll
    for (int i = 0; i < 8; i++)
#pragma unroll
        for (int j = 0; j < 8; j++) acc[i][j] = 0.f;
    float cs[8] = {0.f,0.f,0.f,0.f,0.f,0.f,0.f,0.f};
    int row0 = blockIdx.x * GR_CHUNK;
    for (int rb = 0; rb < GR_CHUNK; rb += 32) {
        __syncthreads();
        for (int i = tid; i < 32 * 128; i += 256) {
            int r = row0 + rb + (i >> 7);
            sF[i >> 7][i & 127] = (r < N_NODES) ? ft[(size_t)r * IN_F + (i & 127)] : 0.f;
        }
        __syncthreads();
        for (int r = 0; r < 32; r++) {
            float a[8], b[8];
#pragma unroll
            for (int i = 0; i < 8; i++) a[i] = sF[r][ty * 8 + i];
#pragma unroll
            for (int j = 0; j < 8; j++) b[j] = sF[r][tx * 8 + j];
#pragma unroll
            for (int i = 0; i < 8; i++)
#pragma unroll
                for (int j = 0; j < 8; j++) acc[i][j] += a[i] * b[j];
            if (ty == 0) {
#pragma unroll
                for (int j = 0; j < 8; j++) cs[j] += b[j];
            }
        }
    }
#pragma unroll
    for (int i = 0; i < 8; i++)
#pragma unroll
        for (int j = 0; j < 8; j++)
            atomicAdd(&G[(ty * 8 + i) * 128 + tx * 8 + j], acc[i][j]);
    if (ty == 0) {
#pragma unroll
        for (int j = 0; j < 8; j++) atomicAdd(&colsum[tx * 8 + j], cs[j]);
    }
}

// ---------------- BN stats from Gram: one block per hidden unit ----------------
__global__ void __launch_bounds__(128) bnstat_k(const float* __restrict__ G,
                                                const float* __restrict__ colsum,
                                                const float* __restrict__ W1,
                                                const float* __restrict__ b1,
                                                const float* __restrict__ gamma,
                                                const float* __restrict__ beta,
                                                float* __restrict__ scale,
                                                float* __restrict__ shift) {
    __shared__ float sw[128];
    __shared__ float red[4];
    int j = blockIdx.x;
    int l = threadIdx.x;
    float wl = W1[(size_t)j * IN_F + l];
    sw[l] = wl;
    __syncthreads();
    // t_l = sum_k sw[k] * G[k][l]   (coalesced over l)
    float t = 0.f;
#pragma unroll 8
    for (int k = 0; k < 128; k++) t += sw[k] * G[k * 128 + l];
    float q = wl * t;            // -> sum_l = W1_j G W1_j^T
    float m = colsum[l] * wl;    // -> sum_l = colsum . W1_j
    // wave reduce (width 64)
#pragma unroll
    for (int off = 32; off >= 1; off >>= 1) {
        q += __shfl_xor(q, off, 64);
        m += __shfl_xor(m, off, 64);
    }
    if ((l & 63) == 0) { red[(l >> 6) * 2] = q; red[(l >> 6) * 2 + 1] = m; }
    __syncthreads();
    if (l == 0) {
        float qq = red[0] + red[2];
        float mm = red[1] + red[3];
        const float invN = 1.f / (float)N_NODES;
        float mean_dot = mm * invN;
        float var = qq * invN - mean_dot * mean_dot;
        float inv = rsqrtf(var + BN_EPS);
        float s = gamma[j] * inv;
        scale[j] = s;
        shift[j] = beta[j] - (mean_dot + b1[j]) * s;
    }
}

// ---------------- weight bf16 pre-conversion ----------------
__global__ void cvtw_k(const float* __restrict__ w1, const float* __restrict__ w2,
                       short* __restrict__ w1b, short* __restrict__ w2b) {
    int i = blockIdx.x * 256 + threadIdx.x;
    if (i < N_HID * IN_F) w1b[i] = f2bf(w1[i]);
    if (i < N_CLS * N_HID) w2b[i] = f2bf(w2[i]);
}

// ---------------- fused fc1 -> BN -> ReLU -> fc2, MFMA ----------------
// block = 128 node-rows, 4 waves; wave = 32-row stripe x 64-col tiles (2x4 frags)
__global__ void __launch_bounds__(256) mlp_k(const float* __restrict__ ft,
                                             const short* __restrict__ w1b,
                                             const float* __restrict__ b1,
                                             const float* __restrict__ scale,
                                             const float* __restrict__ shift,
                                             const short* __restrict__ w2b,
                                             const float* __restrict__ b2,
                                             float* __restrict__ out) {
    __shared__ short sA[128][136];   // 34.8 KB  bf16 ft rows (pad +8 shorts)
    __shared__ short sW1[64][136];   // 17.4 KB  W1 chunk [hid][k]
    __shared__ short sH[128][72];    // 18.4 KB  relu(bn(h)) chunk [row][j]
    __shared__ short sW2[64][72];    //  9.2 KB  W2 chunk [cls][k]

    int tid = threadIdx.x;
    int w   = tid >> 6;        // wave 0..3 -> 32-row stripe
    int l   = tid & 63;
    int q   = l >> 4;          // quad 0..3
    int r16 = l & 15;
    int row0 = blockIdx.x * 128;

    // stage ft rows -> bf16 LDS
    const float4* ft4 = (const float4*)ft;
    for (int i = tid; i < 128 * 32; i += 256) {
        int r = i >> 5, c = i & 31;
        int gr = row0 + r;
        float4 v = {0.f, 0.f, 0.f, 0.f};
        if (gr < N_NODES) v = ft4[(size_t)gr * 32 + c];
        sA[r][c * 4 + 0] = f2bf(v.x);
        sA[r][c * 4 + 1] = f2bf(v.y);
        sA[r][c * 4 + 2] = f2bf(v.z);
        sA[r][c * 4 + 3] = f2bf(v.w);
    }

    floatx4 oacc[2][4];
#pragma unroll
    for (int rt = 0; rt < 2; rt++)
#pragma unroll
        for (int tc = 0; tc < 4; tc++) oacc[rt][tc] = (floatx4){0.f, 0.f, 0.f, 0.f};

    for (int jc = 0; jc < 8; jc++) {
        int j0 = jc * 64;
        __syncthreads();
        // stage W1 chunk [64][128] and W2 chunk [64][64] (bf16, wide loads)
        for (int i = tid; i < 64 * 16; i += 256) {
            int j = i >> 4, k8 = i & 15;
            *(int4*)&sW1[j][k8 * 8] = *(const int4*)&w1b[(size_t)(j0 + j) * IN_F + k8 * 8];
        }
        for (int i = tid; i < 64 * 8; i += 256) {
            int c = i >> 3, k8 = i & 7;
            *(int4*)&sW2[c][k8 * 8] = *(const int4*)&w2b[(size_t)c * N_HID + j0 + k8 * 8];
        }
        __syncthreads();

        // fc1: h[32 x 64] per wave
        floatx4 hacc[2][4];
#pragma unroll
        for (int rt = 0; rt < 2; rt++)
#pragma unroll
            for (int tn = 0; tn < 4; tn++) hacc[rt][tn] = (floatx4){0.f, 0.f, 0.f, 0.f};
#pragma unroll
        for (int ks = 0; ks < 4; ks++) {
            short8 a0 = *(const short8*)&sA[w * 32 + r16][ks * 32 + q * 8];
            short8 a1 = *(const short8*)&sA[w * 32 + 16 + r16][ks * 32 + q * 8];
#pragma unroll
            for (int tn = 0; tn < 4; tn++) {
                short8 b = *(const short8*)&sW1[tn * 16 + r16][ks * 32 + q * 8];
                hacc[0][tn] = __builtin_amdgcn_mfma_f32_16x16x32_bf16(a0, b, hacc[0][tn], 0, 0, 0);
                hacc[1][tn] = __builtin_amdgcn_mfma_f32_16x16x32_bf16(a1, b, hacc[1][tn], 0, 0, 0);
            }
        }
        // BN + ReLU, C-layout -> sH (A-layout source for fc2)
#pragma unroll
        for (int tn = 0; tn < 4; tn++) {
            int col = j0 + tn * 16 + r16;
            float sc = scale[col], sh = shift[col], bb = b1[col];
#pragma unroll
            for (int rt = 0; rt < 2; rt++)
#pragma unroll
                for (int i = 0; i < 4; i++) {
                    float v = (hacc[rt][tn][i] + bb) * sc + sh;
                    sH[w * 32 + rt * 16 + q * 4 + i][tn * 16 + r16] = f2bf(fmaxf(v, 0.f));
                }
        }
        __syncthreads();
        // fc2 partial: oacc += h_chunk @ W2_chunk^T
#pragma unroll
        for (int ks = 0; ks < 2; ks++) {
            short8 a0 = *(const short8*)&sH[w * 32 + r16][ks * 32 + q * 8];
            short8 a1 = *(const short8*)&sH[w * 32 + 16 + r16][ks * 32 + q * 8];
#pragma unroll
            for (int tc = 0; tc < 4; tc++) {
                short8 b = *(const short8*)&sW2[tc * 16 + r16][ks * 32 + q * 8];
                oacc[0][tc] = __builtin_amdgcn_mfma_f32_16x16x32_bf16(a0, b, oacc[0][tc], 0, 0, 0);
                oacc[1][tc] = __builtin_amdgcn_mfma_f32_16x16x32_bf16(a1, b, oacc[1][tc], 0, 0, 0);
            }
        }
    }

    // epilogue
#pragma unroll
    for (int rt = 0; rt < 2; rt++)
#pragma unroll
        for (int tc = 0; tc < 4; tc++) {
            int col = tc * 16 + r16;
            float bb = b2[col];
#pragma unroll
            for (int i = 0; i < 4; i++) {
                int r = row0 + w * 32 + rt * 16 + q * 4 + i;
                if (r < N_NODES) out[(size_t)r * N_CLS + col] = oacc[rt][tc][i] + bb;
            }
        }
}

extern "C" void kernel_launch(void* const* d_in, const int* in_sizes, int n_in,
                              void* d_out, int out_size, void* d_ws, size_t ws_size,
                              hipStream_t stream) {
    const float* feat  = (const float*)d_in[0];
    const int*   src   = (const int*)d_in[1];
    const int*   dst   = (const int*)d_in[2];
    const float* gnorm = (const float*)d_in[3];
    const float* fc1w  = (const float*)d_in[4];
    const float* fc1b  = (const float*)d_in[5];
    const float* gam   = (const float*)d_in[6];
    const float* bet   = (const float*)d_in[7];
    const float* fc2w  = (const float*)d_in[8];
    const float* fc2b  = (const float*)d_in[9];
    float* out = (float*)d_out;

    char* ws = (char*)d_ws;
    const size_t FT_BYTES = (size_t)N_NODES * IN_F * 4;
    size_t off = 0;
    float* ftA    = (float*)(ws + off); off += FT_BYTES;
    float* ftB    = (float*)(ws + off); off += FT_BYTES;
    int*   indptr = (int*)(ws + off);   off += 410112;
    int*   cursor = (int*)(ws + off);   off += 409600;
    int*   ssrc   = (int*)(ws + off);   off += (size_t)N_EDGES * 4;
    float* snorm  = (float*)(ws + off); off += (size_t)N_EDGES * 4;
    float* G      = (float*)(ws + off); off += 128 * 128 * 4;
    float* colsum = (float*)(ws + off); off += 512;
    float* scale  = (float*)(ws + off); off += 2048;
    float* shift  = (float*)(ws + off); off += 2048;
    short* w1b    = (short*)(ws + off); off += (size_t)N_HID * IN_F * 2;
    short* w2b    = (short*)(ws + off); off += (size_t)N_CLS * N_HID * 2;
    (void)ws_size; (void)in_sizes; (void)n_in; (void)out_size;

    hipMemsetAsync(cursor, 0, 409600, stream);
    hipMemsetAsync(G, 0, 128 * 128 * 4 + 512, stream);

    // weight conversion (independent; overlaps CSR build)
    cvtw_k<<<(N_HID * IN_F + 255) / 256, 256, 0, stream>>>(fc1w, fc2w, w1b, w2b);

    // CSR build
    count_k<<<N_EDGES / 256, 256, 0, stream>>>(dst, cursor);
    scan_k<<<1, 1024, 0, stream>>>(cursor, indptr);
    scatter_k<<<N_EDGES / 256, 256, 0, stream>>>(src, dst, gnorm, cursor, ssrc, snorm);

    // 3 propagation hops: feat -> ftA -> ftB -> ftA
    hop_k<<<(N_NODES + 3) / 4, 256, 0, stream>>>((const float4*)feat, (float4*)ftA, indptr, ssrc, snorm);
    hop_k<<<(N_NODES + 3) / 4, 256, 0, stream>>>((const float4*)ftA, (float4*)ftB, indptr, ssrc, snorm);
    hop_k<<<(N_NODES + 3) / 4, 256, 0, stream>>>((const float4*)ftB, (float4*)ftA, indptr, ssrc, snorm);

    // BN stats via Gram matrix
    gram_k<<<(N_NODES + GR_CHUNK - 1) / GR_CHUNK, 256, 0, stream>>>(ftA, G, colsum);
    bnstat_k<<<N_HID, 128, 0, stream>>>(G, colsum, fc1w, fc1b, gam, bet, scale, shift);

    // fused MFMA MLP
    mlp_k<<<(N_NODES + 127) / 128, 256, 0, stream>>>(ftA, w1b, fc1b, scale, shift,
                                                     w2b, fc2b, out);
}

// Round 4
// 757.161 us; speedup vs baseline: 2.5622x; 1.3775x over previous
//
#include <hip/hip_runtime.h>
#include <hip/hip_bf16.h>

#define N_NODES 100000
#define N_EDGES 1600000
#define IN_F    128
#define N_HID   512
#define N_CLS   64
#define BN_EPS  1e-5f
#define NB_GRAM 391   // ceil(100000/256)

typedef __attribute__((ext_vector_type(8))) short short8;
typedef __attribute__((ext_vector_type(4))) float floatx4;

__device__ __forceinline__ short f2bf(float x) {
    union { float f; unsigned u; } t; t.f = x;
    unsigned r = (t.u + 0x7fffu + ((t.u >> 16) & 1u)) >> 16;
    return (short)r;
}
__device__ __forceinline__ float bf2f(short s) {
    union { float f; unsigned u; } t; t.u = ((unsigned)(unsigned short)s) << 16;
    return t.f;
}

// ---------------- CSR build ----------------
__global__ void count_k(const int* __restrict__ dst, int* __restrict__ counts) {
    int e = blockIdx.x * 256 + threadIdx.x;
    if (e < N_EDGES) atomicAdd(&counts[dst[e]], 1);
}

__global__ void __launch_bounds__(1024) scan_k(int* __restrict__ counts, int* __restrict__ indptr) {
    __shared__ int buf[1024];
    __shared__ int s_carry;
    int tid = threadIdx.x;
    if (tid == 0) { s_carry = 0; indptr[0] = 0; }
    __syncthreads();
    for (int base = 0; base < N_NODES; base += 4096) {
        int idx = base + tid * 4;
        int4 v = *(const int4*)(counts + idx);
        int s = v.x + v.y + v.z + v.w;
        buf[tid] = s;
        __syncthreads();
        for (int off = 1; off < 1024; off <<= 1) {
            int t = (tid >= off) ? buf[tid - off] : 0;
            __syncthreads();
            buf[tid] += t;
            __syncthreads();
        }
        int incl  = buf[tid];
        int total = buf[1023];
        int c = s_carry;
        __syncthreads();
        int p = c + incl - s;
        int4 cur;
        cur.x = p;
        cur.y = p + v.x;
        cur.z = p + v.x + v.y;
        cur.w = p + v.x + v.y + v.z;
        *(int4*)(counts + idx) = cur;
        indptr[idx + 1] = cur.y;
        indptr[idx + 2] = cur.z;
        indptr[idx + 3] = cur.w;
        indptr[idx + 4] = p + s;
        if (tid == 0) s_carry = c + total;
        __syncthreads();
    }
}

__global__ void scatter_k(const int* __restrict__ src, const int* __restrict__ dst,
                          const float* __restrict__ norm, int* __restrict__ cursor,
                          int* __restrict__ ssrc, float* __restrict__ snorm) {
    int e = blockIdx.x * 256 + threadIdx.x;
    if (e < N_EDGES) {
        int pos = atomicAdd(&cursor[dst[e]], 1);
        ssrc[pos]  = src[e];
        snorm[pos] = norm[e];
    }
}

// ---------------- propagation hop (fp32 out): one node per wave ----------------
__global__ void __launch_bounds__(256) hop_k(const float4* __restrict__ fin,
                                             float4* __restrict__ fout,
                                             const int* __restrict__ indptr,
                                             const int* __restrict__ ssrc,
                                             const float* __restrict__ snorm) {
    int node = blockIdx.x * 4 + (threadIdx.x >> 6);
    if (node >= N_NODES) return;
    int l    = threadIdx.x & 63;
    int half = l >> 5;
    int c4   = l & 31;
    int beg = indptr[node], end = indptr[node + 1];
    float4 acc = {0.f, 0.f, 0.f, 0.f};
#pragma unroll 2
    for (int e = beg + half; e < end; e += 2) {
        int   s  = ssrc[e];
        float wt = snorm[e];
        float4 v = fin[(size_t)s * 32 + c4];
        acc.x += v.x * wt; acc.y += v.y * wt;
        acc.z += v.z * wt; acc.w += v.w * wt;
    }
    acc.x += __shfl_xor(acc.x, 32, 64);
    acc.y += __shfl_xor(acc.y, 32, 64);
    acc.z += __shfl_xor(acc.z, 32, 64);
    acc.w += __shfl_xor(acc.w, 32, 64);
    if (half == 0) fout[(size_t)node * 32 + c4] = acc;
}

// ---------------- final hop: bf16 output ----------------
__global__ void __launch_bounds__(256) hop_bf_k(const float4* __restrict__ fin,
                                                short* __restrict__ fout,
                                                const int* __restrict__ indptr,
                                                const int* __restrict__ ssrc,
                                                const float* __restrict__ snorm) {
    int node = blockIdx.x * 4 + (threadIdx.x >> 6);
    if (node >= N_NODES) return;
    int l    = threadIdx.x & 63;
    int half = l >> 5;
    int c4   = l & 31;
    int beg = indptr[node], end = indptr[node + 1];
    float4 acc = {0.f, 0.f, 0.f, 0.f};
#pragma unroll 2
    for (int e = beg + half; e < end; e += 2) {
        int   s  = ssrc[e];
        float wt = snorm[e];
        float4 v = fin[(size_t)s * 32 + c4];
        acc.x += v.x * wt; acc.y += v.y * wt;
        acc.z += v.z * wt; acc.w += v.w * wt;
    }
    acc.x += __shfl_xor(acc.x, 32, 64);
    acc.y += __shfl_xor(acc.y, 32, 64);
    acc.z += __shfl_xor(acc.z, 32, 64);
    acc.w += __shfl_xor(acc.w, 32, 64);
    if (half == 0) {
        short4 o;
        o.x = f2bf(acc.x); o.y = f2bf(acc.y);
        o.z = f2bf(acc.z); o.w = f2bf(acc.w);
        *(short4*)&fout[(size_t)node * 128 + c4 * 4] = o;
    }
}

// ---------------- MFMA Gram: Gpart[b] = ftb_chunk^T @ ftb_chunk ----------------
// block = 256 K-rows (8 stages of 32), 4 waves each own a 64x64 quadrant of G
__global__ void __launch_bounds__(256) gram_k(const short* __restrict__ ftb,
                                              float* __restrict__ Gpart,
                                              float* __restrict__ colsum) {
    __shared__ int  sInt[128 * 17];   // [col][row] bf16, 17-int (34-short) stride
    __shared__ float scol[128];
    int tid = threadIdx.x;
    int w   = tid >> 6;
    int l   = tid & 63;
    int q   = l >> 4;
    int r16 = l & 15;
    int i0  = (w >> 1) * 64;
    int j0  = (w & 1) * 64;
    int row0 = blockIdx.x * 256;
    short* sS = (short*)sInt;

    if (tid < 128) scol[tid] = 0.f;

    floatx4 acc[4][4];
#pragma unroll
    for (int a = 0; a < 4; a++)
#pragma unroll
        for (int b = 0; b < 4; b++) acc[a][b] = (floatx4){0.f, 0.f, 0.f, 0.f};
    float colacc[8] = {0.f,0.f,0.f,0.f,0.f,0.f,0.f,0.f};
    int g = tid & 15;   // fixed column group for this thread's staging loads

    for (int st = 0; st < 8; st++) {
        __syncthreads();
        // stage 32 rows x 128 cols, transposed, + colsum accumulation
#pragma unroll
        for (int uu = 0; uu < 2; uu++) {
            int r = (tid >> 4) + uu * 16;
            int gr = row0 + st * 32 + r;
            short v[8];
            if (gr < N_NODES) {
                int4 p = *(const int4*)(ftb + (size_t)gr * 128 + g * 8);
                *(int4*)v = p;
            } else {
#pragma unroll
                for (int d = 0; d < 8; d++) v[d] = 0;
            }
#pragma unroll
            for (int d = 0; d < 8; d++) {
                sS[(g * 8 + d) * 34 + r] = v[d];
                colacc[d] += bf2f(v[d]);
            }
        }
        __syncthreads();
        // MFMA: 4x4 tiles of 16x16, one K=32 step
        short8 af[4], bf[4];
#pragma unroll
        for (int ti = 0; ti < 4; ti++) {
            union { int i[4]; short8 s; } u;
            const int* base = &sInt[(i0 + ti * 16 + r16) * 17 + q * 4];
            u.i[0] = base[0]; u.i[1] = base[1]; u.i[2] = base[2]; u.i[3] = base[3];
            af[ti] = u.s;
        }
#pragma unroll
        for (int tj = 0; tj < 4; tj++) {
            union { int i[4]; short8 s; } u;
            const int* base = &sInt[(j0 + tj * 16 + r16) * 17 + q * 4];
            u.i[0] = base[0]; u.i[1] = base[1]; u.i[2] = base[2]; u.i[3] = base[3];
            bf[tj] = u.s;
        }
#pragma unroll
        for (int ti = 0; ti < 4; ti++)
#pragma unroll
            for (int tj = 0; tj < 4; tj++)
                acc[ti][tj] = __builtin_amdgcn_mfma_f32_16x16x32_bf16(af[ti], bf[tj], acc[ti][tj], 0, 0, 0);
    }

    // store per-block partial G
    float* gp = Gpart + (size_t)blockIdx.x * 16384;
#pragma unroll
    for (int ti = 0; ti < 4; ti++) {
        int gi = i0 + ti * 16 + q * 4;
#pragma unroll
        for (int tj = 0; tj < 4; tj++) {
            int gj = j0 + tj * 16 + r16;
#pragma unroll
            for (int i2 = 0; i2 < 4; i2++)
                gp[(gi + i2) * 128 + gj] = acc[ti][tj][i2];
        }
    }
    // colsum: LDS reduce then one global atomic per column
    __syncthreads();
#pragma unroll
    for (int d = 0; d < 8; d++) atomicAdd(&scol[g * 8 + d], colacc[d]);
    __syncthreads();
    if (tid < 128) atomicAdd(&colsum[tid], scol[tid]);
}

__global__ void __launch_bounds__(256) reduce_k(const float* __restrict__ Gpart,
                                                float* __restrict__ G) {
    int idx = blockIdx.x * 256 + threadIdx.x;
    float s = 0.f;
    for (int b = 0; b < NB_GRAM; b++) s += Gpart[(size_t)b * 16384 + idx];
    G[idx] = s;
}

// ---------------- BN stats from Gram: one block per hidden unit ----------------
__global__ void __launch_bounds__(128) bnstat_k(const float* __restrict__ G,
                                                const float* __restrict__ colsum,
                                                const float* __restrict__ W1,
                                                const float* __restrict__ b1,
                                                const float* __restrict__ gamma,
                                                const float* __restrict__ beta,
                                                float* __restrict__ scale,
                                                float* __restrict__ shift) {
    __shared__ float sw[128];
    __shared__ float red[4];
    int j = blockIdx.x;
    int l = threadIdx.x;
    float wl = W1[(size_t)j * IN_F + l];
    sw[l] = wl;
    __syncthreads();
    float t = 0.f;
#pragma unroll 8
    for (int k = 0; k < 128; k++) t += sw[k] * G[k * 128 + l];
    float q = wl * t;
    float m = colsum[l] * wl;
#pragma unroll
    for (int off = 32; off >= 1; off >>= 1) {
        q += __shfl_xor(q, off, 64);
        m += __shfl_xor(m, off, 64);
    }
    if ((l & 63) == 0) { red[(l >> 6) * 2] = q; red[(l >> 6) * 2 + 1] = m; }
    __syncthreads();
    if (l == 0) {
        float qq = red[0] + red[2];
        float mm = red[1] + red[3];
        const float invN = 1.f / (float)N_NODES;
        float mean_dot = mm * invN;
        float var = qq * invN - mean_dot * mean_dot;
        float inv = rsqrtf(var + BN_EPS);
        float s = gamma[j] * inv;
        scale[j] = s;
        shift[j] = beta[j] - (mean_dot + b1[j]) * s;
    }
}

// ---------------- weight bf16 pre-conversion ----------------
__global__ void cvtw_k(const float* __restrict__ w1, const float* __restrict__ w2,
                       short* __restrict__ w1b, short* __restrict__ w2b) {
    int i = blockIdx.x * 256 + threadIdx.x;
    if (i < N_HID * IN_F) w1b[i] = f2bf(w1[i]);
    if (i < N_CLS * N_HID) w2b[i] = f2bf(w2[i]);
}

// ---------------- fused fc1 -> BN -> ReLU -> fc2, MFMA ----------------
__global__ void __launch_bounds__(256) mlp_k(const short* __restrict__ ftb,
                                             const short* __restrict__ w1b,
                                             const float* __restrict__ b1,
                                             const float* __restrict__ scale,
                                             const float* __restrict__ shift,
                                             const short* __restrict__ w2b,
                                             const float* __restrict__ b2,
                                             float* __restrict__ out) {
    __shared__ short sA[128][136];   // 34.8 KB  bf16 ft rows (pad +8 shorts)
    __shared__ short sW1[64][136];   // 17.4 KB  W1 chunk [hid][k]
    __shared__ short sH[128][72];    // 18.4 KB  relu(bn(h)) chunk [row][j]
    __shared__ short sW2[64][72];    //  9.2 KB  W2 chunk [cls][k]

    int tid = threadIdx.x;
    int w   = tid >> 6;
    int l   = tid & 63;
    int q   = l >> 4;
    int r16 = l & 15;
    int row0 = blockIdx.x * 128;

    // stage bf16 ft rows -> LDS (direct int4 copies)
    for (int i = tid; i < 128 * 16; i += 256) {
        int r = i >> 4, g = i & 15;
        int gr = row0 + r;
        int4 v = {0, 0, 0, 0};
        if (gr < N_NODES) v = *(const int4*)(ftb + (size_t)gr * 128 + g * 8);
        *(int4*)&sA[r][g * 8] = v;
    }

    floatx4 oacc[2][4];
#pragma unroll
    for (int rt = 0; rt < 2; rt++)
#pragma unroll
        for (int tc = 0; tc < 4; tc++) oacc[rt][tc] = (floatx4){0.f, 0.f, 0.f, 0.f};

    for (int jc = 0; jc < 8; jc++) {
        int j0 = jc * 64;
        __syncthreads();
        for (int i = tid; i < 64 * 16; i += 256) {
            int j = i >> 4, k8 = i & 15;
            *(int4*)&sW1[j][k8 * 8] = *(const int4*)&w1b[(size_t)(j0 + j) * IN_F + k8 * 8];
        }
        for (int i = tid; i < 64 * 8; i += 256) {
            int c = i >> 3, k8 = i & 7;
            *(int4*)&sW2[c][k8 * 8] = *(const int4*)&w2b[(size_t)c * N_HID + j0 + k8 * 8];
        }
        __syncthreads();

        floatx4 hacc[2][4];
#pragma unroll
        for (int rt = 0; rt < 2; rt++)
#pragma unroll
            for (int tn = 0; tn < 4; tn++) hacc[rt][tn] = (floatx4){0.f, 0.f, 0.f, 0.f};
#pragma unroll
        for (int ks = 0; ks < 4; ks++) {
            short8 a0 = *(const short8*)&sA[w * 32 + r16][ks * 32 + q * 8];
            short8 a1 = *(const short8*)&sA[w * 32 + 16 + r16][ks * 32 + q * 8];
#pragma unroll
            for (int tn = 0; tn < 4; tn++) {
                short8 b = *(const short8*)&sW1[tn * 16 + r16][ks * 32 + q * 8];
                hacc[0][tn] = __builtin_amdgcn_mfma_f32_16x16x32_bf16(a0, b, hacc[0][tn], 0, 0, 0);
                hacc[1][tn] = __builtin_amdgcn_mfma_f32_16x16x32_bf16(a1, b, hacc[1][tn], 0, 0, 0);
            }
        }
#pragma unroll
        for (int tn = 0; tn < 4; tn++) {
            int col = j0 + tn * 16 + r16;
            float sc = scale[col], sh = shift[col], bb = b1[col];
#pragma unroll
            for (int rt = 0; rt < 2; rt++)
#pragma unroll
                for (int i = 0; i < 4; i++) {
                    float v = (hacc[rt][tn][i] + bb) * sc + sh;
                    sH[w * 32 + rt * 16 + q * 4 + i][tn * 16 + r16] = f2bf(fmaxf(v, 0.f));
                }
        }
        __syncthreads();
#pragma unroll
        for (int ks = 0; ks < 2; ks++) {
            short8 a0 = *(const short8*)&sH[w * 32 + r16][ks * 32 + q * 8];
            short8 a1 = *(const short8*)&sH[w * 32 + 16 + r16][ks * 32 + q * 8];
#pragma unroll
            for (int tc = 0; tc < 4; tc++) {
                short8 b = *(const short8*)&sW2[tc * 16 + r16][ks * 32 + q * 8];
                oacc[0][tc] = __builtin_amdgcn_mfma_f32_16x16x32_bf16(a0, b, oacc[0][tc], 0, 0, 0);
                oacc[1][tc] = __builtin_amdgcn_mfma_f32_16x16x32_bf16(a1, b, oacc[1][tc], 0, 0, 0);
            }
        }
    }

#pragma unroll
    for (int rt = 0; rt < 2; rt++)
#pragma unroll
        for (int tc = 0; tc < 4; tc++) {
            int col = tc * 16 + r16;
            float bb = b2[col];
#pragma unroll
            for (int i = 0; i < 4; i++) {
                int r = row0 + w * 32 + rt * 16 + q * 4 + i;
                if (r < N_NODES) out[(size_t)r * N_CLS + col] = oacc[rt][tc][i] + bb;
            }
        }
}

extern "C" void kernel_launch(void* const* d_in, const int* in_sizes, int n_in,
                              void* d_out, int out_size, void* d_ws, size_t ws_size,
                              hipStream_t stream) {
    const float* feat  = (const float*)d_in[0];
    const int*   src   = (const int*)d_in[1];
    const int*   dst   = (const int*)d_in[2];
    const float* gnorm = (const float*)d_in[3];
    const float* fc1w  = (const float*)d_in[4];
    const float* fc1b  = (const float*)d_in[5];
    const float* gam   = (const float*)d_in[6];
    const float* bet   = (const float*)d_in[7];
    const float* fc2w  = (const float*)d_in[8];
    const float* fc2b  = (const float*)d_in[9];
    float* out = (float*)d_out;

    char* ws = (char*)d_ws;
    const size_t FT_BYTES = (size_t)N_NODES * IN_F * 4;   // 51.2 MB
    size_t off = 0;
    float* ftA    = (float*)(ws + off); off += FT_BYTES;  // hop1 out; later bf16 ftb aliases here
    float* ftB    = (float*)(ws + off); off += FT_BYTES;  // hop2 out; later Gpart aliases here
    int*   indptr = (int*)(ws + off);   off += 410112;
    int*   cursor = (int*)(ws + off);   off += 409600;
    int*   ssrc   = (int*)(ws + off);   off += (size_t)N_EDGES * 4;
    float* snorm  = (float*)(ws + off); off += (size_t)N_EDGES * 4;
    float* G      = (float*)(ws + off); off += 128 * 128 * 4;
    float* colsum = (float*)(ws + off); off += 512;
    float* scale  = (float*)(ws + off); off += 2048;
    float* shift  = (float*)(ws + off); off += 2048;
    short* w1b    = (short*)(ws + off); off += (size_t)N_HID * IN_F * 2;
    short* w2b    = (short*)(ws + off); off += (size_t)N_CLS * N_HID * 2;
    short* ftb    = (short*)ftA;        // bf16 ft, 25.6 MB (ftA free after hop2)
    float* Gpart  = ftB;                // 391*64KB = 25.0 MB (ftB free after hop3)
    (void)ws_size; (void)in_sizes; (void)n_in; (void)out_size;

    hipMemsetAsync(cursor, 0, 409600, stream);
    hipMemsetAsync(colsum, 0, 512, stream);

    cvtw_k<<<(N_HID * IN_F + 255) / 256, 256, 0, stream>>>(fc1w, fc2w, w1b, w2b);

    // CSR build
    count_k<<<N_EDGES / 256, 256, 0, stream>>>(dst, cursor);
    scan_k<<<1, 1024, 0, stream>>>(cursor, indptr);
    scatter_k<<<N_EDGES / 256, 256, 0, stream>>>(src, dst, gnorm, cursor, ssrc, snorm);

    // 3 propagation hops: feat -> ftA -> ftB -> ftb(bf16, aliases ftA)
    hop_k<<<(N_NODES + 3) / 4, 256, 0, stream>>>((const float4*)feat, (float4*)ftA, indptr, ssrc, snorm);
    hop_k<<<(N_NODES + 3) / 4, 256, 0, stream>>>((const float4*)ftA, (float4*)ftB, indptr, ssrc, snorm);
    hop_bf_k<<<(N_NODES + 3) / 4, 256, 0, stream>>>((const float4*)ftB, ftb, indptr, ssrc, snorm);

    // BN stats via MFMA Gram (split-K partials + reduction)
    gram_k<<<NB_GRAM, 256, 0, stream>>>(ftb, Gpart, colsum);
    reduce_k<<<64, 256, 0, stream>>>(Gpart, G);
    bnstat_k<<<N_HID, 128, 0, stream>>>(G, colsum, fc1w, fc1b, gam, bet, scale, shift);

    // fused MFMA MLP
    mlp_k<<<(N_NODES + 127) / 128, 256, 0, stream>>>(ftb, w1b, fc1b, scale, shift,
                                                     w2b, fc2b, out);
}

// Round 6
// 628.715 us; speedup vs baseline: 3.0857x; 1.2043x over previous
//
#include <hip/hip_runtime.h>
#include <hip/hip_bf16.h>

#define N_NODES 100000
#define N_EDGES 1600000
#define IN_F    128
#define N_HID   512
#define N_CLS   64
#define BN_EPS  1e-5f
#define NB_GRAM 391   // ceil(100000/256)
#define SCAN_PAD 114688  // 7 * 16384

typedef __attribute__((ext_vector_type(8))) short short8;
typedef __attribute__((ext_vector_type(4))) float floatx4;

__device__ __forceinline__ short f2bf(float x) {
    union { float f; unsigned u; } t; t.f = x;
    unsigned r = (t.u + 0x7fffu + ((t.u >> 16) & 1u)) >> 16;
    return (short)r;
}
__device__ __forceinline__ float bf2f(short s) {
    union { float f; unsigned u; } t; t.u = ((unsigned)(unsigned short)s) << 16;
    return t.f;
}

// ---------------- feat fp32 -> bf16 ----------------
__global__ void cvtf_k(const float4* __restrict__ f, short* __restrict__ o) {
    int i = blockIdx.x * 256 + threadIdx.x;   // 3.2M threads, exact
    float4 v = f[i];
    short4 s;
    s.x = f2bf(v.x); s.y = f2bf(v.y); s.z = f2bf(v.z); s.w = f2bf(v.w);
    *(short4*)(o + (size_t)i * 4) = s;
}

// ---------------- CSR build ----------------
__global__ void count_k(const int* __restrict__ dst, int* __restrict__ counts) {
    int e = blockIdx.x * 256 + threadIdx.x;
    if (e < N_EDGES) atomicAdd(&counts[dst[e]], 1);
}

// 1024 threads, 16 elems/thread, shfl-scan. counts(padded,zeroed) -> cursor; writes indptr
__global__ void __launch_bounds__(1024) scan_k(int* __restrict__ counts, int* __restrict__ indptr) {
    __shared__ int wsum[16];
    __shared__ int s_carry;
    int tid = threadIdx.x;
    int lane = tid & 63, wid = tid >> 6;
    if (tid == 0) { s_carry = 0; indptr[0] = 0; }
    __syncthreads();
    for (int base = 0; base < SCAN_PAD; base += 16384) {
        int idx = base + tid * 16;
        int vv[16];
#pragma unroll
        for (int u = 0; u < 4; u++) {
            int4 v = *(const int4*)(counts + idx + u * 4);
            vv[u * 4 + 0] = v.x; vv[u * 4 + 1] = v.y;
            vv[u * 4 + 2] = v.z; vv[u * 4 + 3] = v.w;
        }
        int s = 0;
#pragma unroll
        for (int u = 0; u < 16; u++) s += vv[u];
        int sc = s;
#pragma unroll
        for (int off = 1; off < 64; off <<= 1) {
            int t = __shfl_up(sc, off, 64);
            if (lane >= off) sc += t;
        }
        if (lane == 63) wsum[wid] = sc;
        __syncthreads();
        if (wid == 0) {
            int wv = (lane < 16) ? wsum[lane] : 0;
#pragma unroll
            for (int off = 1; off < 16; off <<= 1) {
                int t = __shfl_up(wv, off, 64);
                if (lane >= off) wv += t;
            }
            if (lane < 16) wsum[lane] = wv;
        }
        __syncthreads();
        int carry = s_carry;
        int wave_excl = (wid == 0) ? 0 : wsum[wid - 1];
        int run = carry + wave_excl + (sc - s);
#pragma unroll
        for (int u = 0; u < 16; u++) {
            int t = vv[u];
            vv[u] = run;
            run += t;
            indptr[idx + u + 1] = run;
        }
#pragma unroll
        for (int u = 0; u < 4; u++) {
            int4 o = {vv[u * 4 + 0], vv[u * 4 + 1], vv[u * 4 + 2], vv[u * 4 + 3]};
            *(int4*)(counts + idx + u * 4) = o;
        }
        __syncthreads();   // all read carry/wsum
        if (tid == 0) s_carry = carry + wsum[15];
        __syncthreads();
    }
}

__global__ void scatter_k(const int* __restrict__ src, const int* __restrict__ dst,
                          const float* __restrict__ norm, int* __restrict__ cursor,
                          int2* __restrict__ sedge) {
    int e = blockIdx.x * 256 + threadIdx.x;
    if (e < N_EDGES) {
        int pos = atomicAdd(&cursor[dst[e]], 1);
        int2 p; p.x = src[e]; p.y = __float_as_int(norm[e]);
        sedge[pos] = p;
    }
}

// ---------------- bf16 propagation hop: one node per wave, 4 edges in flight ----
__global__ void __launch_bounds__(256) hopb_k(const short* __restrict__ fin,
                                              short* __restrict__ fout,
                                              const int* __restrict__ indptr,
                                              const int2* __restrict__ sedge) {
    int node = blockIdx.x * 4 + (threadIdx.x >> 6);
    if (node >= N_NODES) return;
    int l  = threadIdx.x & 63;
    int q4 = l >> 4;    // edge slot 0..3
    int c  = l & 15;    // int4 chunk within 256B row
    int beg = indptr[node], end = indptr[node + 1];
    float acc[8] = {0.f,0.f,0.f,0.f,0.f,0.f,0.f,0.f};
    for (int e = beg + q4; e < end; e += 4) {
        int2 ed = sedge[e];
        float wt = __int_as_float(ed.y);
        short sv[8];
        *(int4*)sv = *(const int4*)(fin + (size_t)ed.x * 128 + c * 8);
#pragma unroll
        for (int d = 0; d < 8; d++) acc[d] += bf2f(sv[d]) * wt;
    }
#pragma unroll
    for (int d = 0; d < 8; d++) {
        acc[d] += __shfl_xor(acc[d], 16, 64);
        acc[d] += __shfl_xor(acc[d], 32, 64);
    }
    if (q4 == 0) {
        short sv[8];
#pragma unroll
        for (int d = 0; d < 8; d++) sv[d] = f2bf(acc[d]);
        *(int4*)(fout + (size_t)node * 128 + c * 8) = *(int4*)sv;
    }
}

// ---------------- MFMA Gram: Gpart[b] = ftb_chunk^T @ ftb_chunk ----------------
__global__ void __launch_bounds__(256) gram_k(const short* __restrict__ ftb,
                                              float* __restrict__ Gpart,
                                              float* __restrict__ colsum) {
    __shared__ int  sInt[128 * 17];   // [col][row] bf16, 17-int (34-short) stride
    __shared__ float scol[128];
    int tid = threadIdx.x;
    int w   = tid >> 6;
    int l   = tid & 63;
    int q   = l >> 4;
    int r16 = l & 15;
    int i0  = (w >> 1) * 64;
    int j0  = (w & 1) * 64;
    int row0 = blockIdx.x * 256;
    short* sS = (short*)sInt;

    if (tid < 128) scol[tid] = 0.f;

    floatx4 acc[4][4];
#pragma unroll
    for (int a = 0; a < 4; a++)
#pragma unroll
        for (int b = 0; b < 4; b++) acc[a][b] = (floatx4){0.f, 0.f, 0.f, 0.f};
    float colacc[8] = {0.f,0.f,0.f,0.f,0.f,0.f,0.f,0.f};
    int g = tid & 15;

    for (int st = 0; st < 8; st++) {
        __syncthreads();
#pragma unroll
        for (int uu = 0; uu < 2; uu++) {
            int r = (tid >> 4) + uu * 16;
            int gr = row0 + st * 32 + r;
            short v[8];
            if (gr < N_NODES) {
                *(int4*)v = *(const int4*)(ftb + (size_t)gr * 128 + g * 8);
            } else {
#pragma unroll
                for (int d = 0; d < 8; d++) v[d] = 0;
            }
#pragma unroll
            for (int d = 0; d < 8; d++) {
                sS[(g * 8 + d) * 34 + r] = v[d];
                colacc[d] += bf2f(v[d]);
            }
        }
        __syncthreads();
        short8 af[4], bf[4];
#pragma unroll
        for (int ti = 0; ti < 4; ti++) {
            union { int i[4]; short8 s; } u;
            const int* base = &sInt[(i0 + ti * 16 + r16) * 17 + q * 4];
            u.i[0] = base[0]; u.i[1] = base[1]; u.i[2] = base[2]; u.i[3] = base[3];
            af[ti] = u.s;
        }
#pragma unroll
        for (int tj = 0; tj < 4; tj++) {
            union { int i[4]; short8 s; } u;
            const int* base = &sInt[(j0 + tj * 16 + r16) * 17 + q * 4];
            u.i[0] = base[0]; u.i[1] = base[1]; u.i[2] = base[2]; u.i[3] = base[3];
            bf[tj] = u.s;
        }
#pragma unroll
        for (int ti = 0; ti < 4; ti++)
#pragma unroll
            for (int tj = 0; tj < 4; tj++)
                acc[ti][tj] = __builtin_amdgcn_mfma_f32_16x16x32_bf16(af[ti], bf[tj], acc[ti][tj], 0, 0, 0);
    }

    float* gp = Gpart + (size_t)blockIdx.x * 16384;
#pragma unroll
    for (int ti = 0; ti < 4; ti++) {
        int gi = i0 + ti * 16 + q * 4;
#pragma unroll
        for (int tj = 0; tj < 4; tj++) {
            int gj = j0 + tj * 16 + r16;
#pragma unroll
            for (int i2 = 0; i2 < 4; i2++)
                gp[(gi + i2) * 128 + gj] = acc[ti][tj][i2];
        }
    }
    __syncthreads();
#pragma unroll
    for (int d = 0; d < 8; d++) atomicAdd(&scol[g * 8 + d], colacc[d]);
    __syncthreads();
    if (tid < 128) atomicAdd(&colsum[tid], scol[tid]);
}

__global__ void __launch_bounds__(256) reduce_k(const float* __restrict__ Gpart,
                                                float* __restrict__ G) {
    int idx = blockIdx.x * 256 + threadIdx.x;
    float s = 0.f;
    for (int b = 0; b < NB_GRAM; b++) s += Gpart[(size_t)b * 16384 + idx];
    G[idx] = s;
}

// ---------------- BN stats from Gram: one block per hidden unit ----------------
__global__ void __launch_bounds__(128) bnstat_k(const float* __restrict__ G,
                                                const float* __restrict__ colsum,
                                                const float* __restrict__ W1,
                                                const float* __restrict__ b1,
                                                const float* __restrict__ gamma,
                                                const float* __restrict__ beta,
                                                float* __restrict__ scale,
                                                float* __restrict__ shift) {
    __shared__ float sw[128];
    __shared__ float red[4];
    int j = blockIdx.x;
    int l = threadIdx.x;
    float wl = W1[(size_t)j * IN_F + l];
    sw[l] = wl;
    __syncthreads();
    float t = 0.f;
#pragma unroll 8
    for (int k = 0; k < 128; k++) t += sw[k] * G[k * 128 + l];
    float q = wl * t;
    float m = colsum[l] * wl;
#pragma unroll
    for (int off = 32; off >= 1; off >>= 1) {
        q += __shfl_xor(q, off, 64);
        m += __shfl_xor(m, off, 64);
    }
    if ((l & 63) == 0) { red[(l >> 6) * 2] = q; red[(l >> 6) * 2 + 1] = m; }
    __syncthreads();
    if (l == 0) {
        float qq = red[0] + red[2];
        float mm = red[1] + red[3];
        const float invN = 1.f / (float)N_NODES;
        float mean_dot = mm * invN;
        float var = qq * invN - mean_dot * mean_dot;
        float inv = rsqrtf(var + BN_EPS);
        float s = gamma[j] * inv;
        scale[j] = s;
        shift[j] = beta[j] - (mean_dot + b1[j]) * s;
    }
}

// ---------------- weight bf16 pre-conversion ----------------
__global__ void cvtw_k(const float* __restrict__ w1, const float* __restrict__ w2,
                       short* __restrict__ w1b, short* __restrict__ w2b) {
    int i = blockIdx.x * 256 + threadIdx.x;
    if (i < N_HID * IN_F) w1b[i] = f2bf(w1[i]);
    if (i < N_CLS * N_HID) w2b[i] = f2bf(w2[i]);
}

// ---------------- fused fc1 -> BN -> ReLU -> fc2, MFMA ----------------
__global__ void __launch_bounds__(256) mlp_k(const short* __restrict__ ftb,
                                             const short* __restrict__ w1b,
                                             const float* __restrict__ b1,
                                             const float* __restrict__ scale,
                                             const float* __restrict__ shift,
                                             const short* __restrict__ w2b,
                                             const float* __restrict__ b2,
                                             float* __restrict__ out) {
    __shared__ short sA[128][136];
    __shared__ short sW1[64][136];
    __shared__ short sH[128][72];
    __shared__ short sW2[64][72];

    int tid = threadIdx.x;
    int w   = tid >> 6;
    int l   = tid & 63;
    int q   = l >> 4;
    int r16 = l & 15;
    int row0 = blockIdx.x * 128;

    for (int i = tid; i < 128 * 16; i += 256) {
        int r = i >> 4, g = i & 15;
        int gr = row0 + r;
        int4 v = {0, 0, 0, 0};
        if (gr < N_NODES) v = *(const int4*)(ftb + (size_t)gr * 128 + g * 8);
        *(int4*)&sA[r][g * 8] = v;
    }

    floatx4 oacc[2][4];
#pragma unroll
    for (int rt = 0; rt < 2; rt++)
#pragma unroll
        for (int tc = 0; tc < 4; tc++) oacc[rt][tc] = (floatx4){0.f, 0.f, 0.f, 0.f};

    for (int jc = 0; jc < 8; jc++) {
        int j0 = jc * 64;
        __syncthreads();
        for (int i = tid; i < 64 * 16; i += 256) {
            int j = i >> 4, k8 = i & 15;
            *(int4*)&sW1[j][k8 * 8] = *(const int4*)&w1b[(size_t)(j0 + j) * IN_F + k8 * 8];
        }
        for (int i = tid; i < 64 * 8; i += 256) {
            int c = i >> 3, k8 = i & 7;
            *(int4*)&sW2[c][k8 * 8] = *(const int4*)&w2b[(size_t)c * N_HID + j0 + k8 * 8];
        }
        __syncthreads();

        floatx4 hacc[2][4];
#pragma unroll
        for (int rt = 0; rt < 2; rt++)
#pragma unroll
            for (int tn = 0; tn < 4; tn++) hacc[rt][tn] = (floatx4){0.f, 0.f, 0.f, 0.f};
#pragma unroll
        for (int ks = 0; ks < 4; ks++) {
            short8 a0 = *(const short8*)&sA[w * 32 + r16][ks * 32 + q * 8];
            short8 a1 = *(const short8*)&sA[w * 32 + 16 + r16][ks * 32 + q * 8];
#pragma unroll
            for (int tn = 0; tn < 4; tn++) {
                short8 b = *(const short8*)&sW1[tn * 16 + r16][ks * 32 + q * 8];
                hacc[0][tn] = __builtin_amdgcn_mfma_f32_16x16x32_bf16(a0, b, hacc[0][tn], 0, 0, 0);
                hacc[1][tn] = __builtin_amdgcn_mfma_f32_16x16x32_bf16(a1, b, hacc[1][tn], 0, 0, 0);
            }
        }
#pragma unroll
        for (int tn = 0; tn < 4; tn++) {
            int col = j0 + tn * 16 + r16;
            float sc = scale[col], sh = shift[col], bb = b1[col];
#pragma unroll
            for (int rt = 0; rt < 2; rt++)
#pragma unroll
                for (int i = 0; i < 4; i++) {
                    float v = (hacc[rt][tn][i] + bb) * sc + sh;
                    sH[w * 32 + rt * 16 + q * 4 + i][tn * 16 + r16] = f2bf(fmaxf(v, 0.f));
                }
        }
        __syncthreads();
#pragma unroll
        for (int ks = 0; ks < 2; ks++) {
            short8 a0 = *(const short8*)&sH[w * 32 + r16][ks * 32 + q * 8];
            short8 a1 = *(const short8*)&sH[w * 32 + 16 + r16][ks * 32 + q * 8];
#pragma unroll
            for (int tc = 0; tc < 4; tc++) {
                short8 b = *(const short8*)&sW2[tc * 16 + r16][ks * 32 + q * 8];
                oacc[0][tc] = __builtin_amdgcn_mfma_f32_16x16x32_bf16(a0, b, oacc[0][tc], 0, 0, 0);
                oacc[1][tc] = __builtin_amdgcn_mfma_f32_16x16x32_bf16(a1, b, oacc[1][tc], 0, 0, 0);
            }
        }
    }

#pragma unroll
    for (int rt = 0; rt < 2; rt++)
#pragma unroll
        for (int tc = 0; tc < 4; tc++) {
            int col = tc * 16 + r16;
            float bb = b2[col];
#pragma unroll
            for (int i = 0; i < 4; i++) {
                int r = row0 + w * 32 + rt * 16 + q * 4 + i;
                if (r < N_NODES) out[(size_t)r * N_CLS + col] = oacc[rt][tc][i] + bb;
            }
        }
}

extern "C" void kernel_launch(void* const* d_in, const int* in_sizes, int n_in,
                              void* d_out, int out_size, void* d_ws, size_t ws_size,
                              hipStream_t stream) {
    const float* feat  = (const float*)d_in[0];
    const int*   src   = (const int*)d_in[1];
    const int*   dst   = (const int*)d_in[2];
    const float* gnorm = (const float*)d_in[3];
    const float* fc1w  = (const float*)d_in[4];
    const float* fc1b  = (const float*)d_in[5];
    const float* gam   = (const float*)d_in[6];
    const float* bet   = (const float*)d_in[7];
    const float* fc2w  = (const float*)d_in[8];
    const float* fc2b  = (const float*)d_in[9];
    float* out = (float*)d_out;

    char* ws = (char*)d_ws;
    const size_t FTB_BYTES = (size_t)N_NODES * IN_F * 2;   // 25.6 MB
    size_t off = 0;
    short* bufA   = (short*)(ws + off); off += FTB_BYTES;  // featb
    short* bufB   = (short*)(ws + off); off += FTB_BYTES;  // ft1b; ft3b aliases after hop2
    short* bufC   = (short*)(ws + off); off += FTB_BYTES;  // ft2b
    int*   indptr = (int*)(ws + off);   off += 460800;     // up to 114689 ints
    int*   cursor = (int*)(ws + off);   off += SCAN_PAD * 4;   // 458752 B, zeroed
    int2*  sedge  = (int2*)(ws + off);  off += (size_t)N_EDGES * 8;
    float* G      = (float*)(ws + off); off += 128 * 128 * 4;
    float* colsum = (float*)(ws + off); off += 512;
    float* scale  = (float*)(ws + off); off += 2048;
    float* shift  = (float*)(ws + off); off += 2048;
    short* w1b    = (short*)(ws + off); off += (size_t)N_HID * IN_F * 2;
    short* w2b    = (short*)(ws + off); off += (size_t)N_CLS * N_HID * 2;
    // FIX (round 5 bug): Gpart needs NB_GRAM*64KB = 25,624,576 B — that is
    // LARGER than a bf16 ft buffer (25,600,000 B). Aliasing it onto bufA
    // overflowed 24 KB into bufB (= ft3b), corrupting the first 96 node rows
    // with fp32 bit patterns (absmax 3.2e36). Dedicated region instead.
    float* Gpart  = (float*)(ws + off); off += (size_t)NB_GRAM * 16384 * 4;
    short* featb  = bufA;
    short* ft1b   = bufB;
    short* ft2b   = bufC;
    short* ft3b   = bufB;               // reuse (ft1b dead after hop2)
    (void)ws_size; (void)in_sizes; (void)n_in; (void)out_size;

    hipMemsetAsync(cursor, 0, SCAN_PAD * 4, stream);
    hipMemsetAsync(colsum, 0, 512, stream);

    cvtf_k<<<12500, 256, 0, stream>>>((const float4*)feat, featb);
    cvtw_k<<<(N_HID * IN_F + 255) / 256, 256, 0, stream>>>(fc1w, fc2w, w1b, w2b);

    // CSR build
    count_k<<<N_EDGES / 256, 256, 0, stream>>>(dst, cursor);
    scan_k<<<1, 1024, 0, stream>>>(cursor, indptr);
    scatter_k<<<N_EDGES / 256, 256, 0, stream>>>(src, dst, gnorm, cursor, sedge);

    // 3 bf16 propagation hops: featb -> ft1b -> ft2b -> ft3b
    hopb_k<<<(N_NODES + 3) / 4, 256, 0, stream>>>(featb, ft1b, indptr, sedge);
    hopb_k<<<(N_NODES + 3) / 4, 256, 0, stream>>>(ft1b, ft2b, indptr, sedge);
    hopb_k<<<(N_NODES + 3) / 4, 256, 0, stream>>>(ft2b, ft3b, indptr, sedge);

    // BN stats via MFMA Gram (split-K partials + reduction)
    gram_k<<<NB_GRAM, 256, 0, stream>>>(ft3b, Gpart, colsum);
    reduce_k<<<64, 256, 0, stream>>>(Gpart, G);
    bnstat_k<<<N_HID, 128, 0, stream>>>(G, colsum, fc1w, fc1b, gam, bet, scale, shift);

    // fused MFMA MLP
    mlp_k<<<(N_NODES + 127) / 128, 256, 0, stream>>>(ft3b, w1b, fc1b, scale, shift,
                                                     w2b, fc2b, out);
}

// Round 7
// 609.098 us; speedup vs baseline: 3.1851x; 1.0322x over previous
//
#include <hip/hip_runtime.h>
#include <hip/hip_bf16.h>

#define N_NODES 100000
#define N_EDGES 1600000
#define IN_F    128
#define N_HID   512
#define N_CLS   64
#define BN_EPS  1e-5f
#define NB_GRAM 391   // ceil(100000/256)
#define SCAN_PAD 114688  // 7 * 16384

typedef __attribute__((ext_vector_type(8))) short short8;
typedef __attribute__((ext_vector_type(4))) float floatx4;

__device__ __forceinline__ short f2bf(float x) {
    union { float f; unsigned u; } t; t.f = x;
    unsigned r = (t.u + 0x7fffu + ((t.u >> 16) & 1u)) >> 16;
    return (short)r;
}
__device__ __forceinline__ float bf2f(short s) {
    union { float f; unsigned u; } t; t.u = ((unsigned)(unsigned short)s) << 16;
    return t.f;
}

// ---------------- feat fp32 -> bf16 ----------------
__global__ void cvtf_k(const float4* __restrict__ f, short* __restrict__ o) {
    int i = blockIdx.x * 256 + threadIdx.x;   // 3.2M threads, exact
    float4 v = f[i];
    short4 s;
    s.x = f2bf(v.x); s.y = f2bf(v.y); s.z = f2bf(v.z); s.w = f2bf(v.w);
    *(short4*)(o + (size_t)i * 4) = s;
}

// ---------------- CSR build ----------------
__global__ void count_k(const int* __restrict__ dst, int* __restrict__ counts) {
    int e = blockIdx.x * 256 + threadIdx.x;
    if (e < N_EDGES) atomicAdd(&counts[dst[e]], 1);
}

// 1024 threads, 16 elems/thread, shfl-scan. counts(padded,zeroed) -> cursor; writes indptr
__global__ void __launch_bounds__(1024) scan_k(int* __restrict__ counts, int* __restrict__ indptr) {
    __shared__ int wsum[16];
    __shared__ int s_carry;
    int tid = threadIdx.x;
    int lane = tid & 63, wid = tid >> 6;
    if (tid == 0) { s_carry = 0; indptr[0] = 0; }
    __syncthreads();
    for (int base = 0; base < SCAN_PAD; base += 16384) {
        int idx = base + tid * 16;
        int vv[16];
#pragma unroll
        for (int u = 0; u < 4; u++) {
            int4 v = *(const int4*)(counts + idx + u * 4);
            vv[u * 4 + 0] = v.x; vv[u * 4 + 1] = v.y;
            vv[u * 4 + 2] = v.z; vv[u * 4 + 3] = v.w;
        }
        int s = 0;
#pragma unroll
        for (int u = 0; u < 16; u++) s += vv[u];
        int sc = s;
#pragma unroll
        for (int off = 1; off < 64; off <<= 1) {
            int t = __shfl_up(sc, off, 64);
            if (lane >= off) sc += t;
        }
        if (lane == 63) wsum[wid] = sc;
        __syncthreads();
        if (wid == 0) {
            int wv = (lane < 16) ? wsum[lane] : 0;
#pragma unroll
            for (int off = 1; off < 16; off <<= 1) {
                int t = __shfl_up(wv, off, 64);
                if (lane >= off) wv += t;
            }
            if (lane < 16) wsum[lane] = wv;
        }
        __syncthreads();
        int carry = s_carry;
        int wave_excl = (wid == 0) ? 0 : wsum[wid - 1];
        int run = carry + wave_excl + (sc - s);
#pragma unroll
        for (int u = 0; u < 16; u++) {
            int t = vv[u];
            vv[u] = run;
            run += t;
            indptr[idx + u + 1] = run;
        }
#pragma unroll
        for (int u = 0; u < 4; u++) {
            int4 o = {vv[u * 4 + 0], vv[u * 4 + 1], vv[u * 4 + 2], vv[u * 4 + 3]};
            *(int4*)(counts + idx + u * 4) = o;
        }
        __syncthreads();   // all read carry/wsum
        if (tid == 0) s_carry = carry + wsum[15];
        __syncthreads();
    }
}

// packed edge: (src << 15) | round(norm * 32768) clamped to 15 bits.
// src < 131072 (17b), norm in [0,1): abs err <= 3e-5 on the weight —
// 2 orders below the bf16 rounding of ft itself. Halves sedge lines.
__global__ void scatter_k(const int* __restrict__ src, const int* __restrict__ dst,
                          const float* __restrict__ norm, int* __restrict__ cursor,
                          unsigned* __restrict__ sedge) {
    int e = blockIdx.x * 256 + threadIdx.x;
    if (e < N_EDGES) {
        int pos = atomicAdd(&cursor[dst[e]], 1);
        unsigned qn = (unsigned)fminf(norm[e] * 32768.f + 0.5f, 32767.f);
        sedge[pos] = ((unsigned)src[e] << 15) | qn;
    }
}

// ---------------- bf16 propagation hop: one node per wave, 4 edges in flight ----
__global__ void __launch_bounds__(256) hopb_k(const short* __restrict__ fin,
                                              short* __restrict__ fout,
                                              const int* __restrict__ indptr,
                                              const unsigned* __restrict__ sedge) {
    int node = blockIdx.x * 4 + (threadIdx.x >> 6);
    if (node >= N_NODES) return;
    int l  = threadIdx.x & 63;
    int q4 = l >> 4;    // edge slot 0..3
    int c  = l & 15;    // int4 chunk within 256B row
    int beg = indptr[node], end = indptr[node + 1];
    float acc[8] = {0.f,0.f,0.f,0.f,0.f,0.f,0.f,0.f};
    for (int e = beg + q4; e < end; e += 4) {
        unsigned ed = sedge[e];
        float wt = (float)(ed & 32767u) * (1.f / 32768.f);
        unsigned s = ed >> 15;
        short sv[8];
        *(int4*)sv = *(const int4*)(fin + (size_t)s * 128 + c * 8);
#pragma unroll
        for (int d = 0; d < 8; d++) acc[d] += bf2f(sv[d]) * wt;
    }
#pragma unroll
    for (int d = 0; d < 8; d++) {
        acc[d] += __shfl_xor(acc[d], 16, 64);
        acc[d] += __shfl_xor(acc[d], 32, 64);
    }
    if (q4 == 0) {
        short sv[8];
#pragma unroll
        for (int d = 0; d < 8; d++) sv[d] = f2bf(acc[d]);
        *(int4*)(fout + (size_t)node * 128 + c * 8) = *(int4*)sv;
    }
}

// ---------------- MFMA Gram: Gpart[b] = ftb_chunk^T @ ftb_chunk ----------------
__global__ void __launch_bounds__(256) gram_k(const short* __restrict__ ftb,
                                              float* __restrict__ Gpart,
                                              float* __restrict__ colsum) {
    __shared__ int  sInt[128 * 17];   // [col][row] bf16, 17-int (34-short) stride
    __shared__ float scol[128];
    int tid = threadIdx.x;
    int w   = tid >> 6;
    int l   = tid & 63;
    int q   = l >> 4;
    int r16 = l & 15;
    int i0  = (w >> 1) * 64;
    int j0  = (w & 1) * 64;
    int row0 = blockIdx.x * 256;
    short* sS = (short*)sInt;

    if (tid < 128) scol[tid] = 0.f;

    floatx4 acc[4][4];
#pragma unroll
    for (int a = 0; a < 4; a++)
#pragma unroll
        for (int b = 0; b < 4; b++) acc[a][b] = (floatx4){0.f, 0.f, 0.f, 0.f};
    float colacc[8] = {0.f,0.f,0.f,0.f,0.f,0.f,0.f,0.f};
    int g = tid & 15;

    for (int st = 0; st < 8; st++) {
        __syncthreads();
#pragma unroll
        for (int uu = 0; uu < 2; uu++) {
            int r = (tid >> 4) + uu * 16;
            int gr = row0 + st * 32 + r;
            short v[8];
            if (gr < N_NODES) {
                *(int4*)v = *(const int4*)(ftb + (size_t)gr * 128 + g * 8);
            } else {
#pragma unroll
                for (int d = 0; d < 8; d++) v[d] = 0;
            }
#pragma unroll
            for (int d = 0; d < 8; d++) {
                sS[(g * 8 + d) * 34 + r] = v[d];
                colacc[d] += bf2f(v[d]);
            }
        }
        __syncthreads();
        short8 af[4], bf[4];
#pragma unroll
        for (int ti = 0; ti < 4; ti++) {
            union { int i[4]; short8 s; } u;
            const int* base = &sInt[(i0 + ti * 16 + r16) * 17 + q * 4];
            u.i[0] = base[0]; u.i[1] = base[1]; u.i[2] = base[2]; u.i[3] = base[3];
            af[ti] = u.s;
        }
#pragma unroll
        for (int tj = 0; tj < 4; tj++) {
            union { int i[4]; short8 s; } u;
            const int* base = &sInt[(j0 + tj * 16 + r16) * 17 + q * 4];
            u.i[0] = base[0]; u.i[1] = base[1]; u.i[2] = base[2]; u.i[3] = base[3];
            bf[tj] = u.s;
        }
#pragma unroll
        for (int ti = 0; ti < 4; ti++)
#pragma unroll
            for (int tj = 0; tj < 4; tj++)
                acc[ti][tj] = __builtin_amdgcn_mfma_f32_16x16x32_bf16(af[ti], bf[tj], acc[ti][tj], 0, 0, 0);
    }

    float* gp = Gpart + (size_t)blockIdx.x * 16384;
#pragma unroll
    for (int ti = 0; ti < 4; ti++) {
        int gi = i0 + ti * 16 + q * 4;
#pragma unroll
        for (int tj = 0; tj < 4; tj++) {
            int gj = j0 + tj * 16 + r16;
#pragma unroll
            for (int i2 = 0; i2 < 4; i2++)
                gp[(gi + i2) * 128 + gj] = acc[ti][tj][i2];
        }
    }
    __syncthreads();
#pragma unroll
    for (int d = 0; d < 8; d++) atomicAdd(&scol[g * 8 + d], colacc[d]);
    __syncthreads();
    if (tid < 128) atomicAdd(&colsum[tid], scol[tid]);
}

__global__ void __launch_bounds__(256) reduce_k(const float* __restrict__ Gpart,
                                                float* __restrict__ G) {
    int idx = blockIdx.x * 256 + threadIdx.x;
    float s = 0.f;
    for (int b = 0; b < NB_GRAM; b++) s += Gpart[(size_t)b * 16384 + idx];
    G[idx] = s;
}

// ---------------- BN stats from Gram: one block per hidden unit ----------------
__global__ void __launch_bounds__(128) bnstat_k(const float* __restrict__ G,
                                                const float* __restrict__ colsum,
                                                const float* __restrict__ W1,
                                                const float* __restrict__ b1,
                                                const float* __restrict__ gamma,
                                                const float* __restrict__ beta,
                                                float* __restrict__ scale,
                                                float* __restrict__ shift) {
    __shared__ float sw[128];
    __shared__ float red[4];
    int j = blockIdx.x;
    int l = threadIdx.x;
    float wl = W1[(size_t)j * IN_F + l];
    sw[l] = wl;
    __syncthreads();
    float t = 0.f;
#pragma unroll 8
    for (int k = 0; k < 128; k++) t += sw[k] * G[k * 128 + l];
    float q = wl * t;
    float m = colsum[l] * wl;
#pragma unroll
    for (int off = 32; off >= 1; off >>= 1) {
        q += __shfl_xor(q, off, 64);
        m += __shfl_xor(m, off, 64);
    }
    if ((l & 63) == 0) { red[(l >> 6) * 2] = q; red[(l >> 6) * 2 + 1] = m; }
    __syncthreads();
    if (l == 0) {
        float qq = red[0] + red[2];
        float mm = red[1] + red[3];
        const float invN = 1.f / (float)N_NODES;
        float mean_dot = mm * invN;
        float var = qq * invN - mean_dot * mean_dot;
        float inv = rsqrtf(var + BN_EPS);
        float s = gamma[j] * inv;
        scale[j] = s;
        shift[j] = beta[j] - (mean_dot + b1[j]) * s;
    }
}

// ---------------- weight bf16 pre-conversion ----------------
__global__ void cvtw_k(const float* __restrict__ w1, const float* __restrict__ w2,
                       short* __restrict__ w1b, short* __restrict__ w2b) {
    int i = blockIdx.x * 256 + threadIdx.x;
    if (i < N_HID * IN_F) w1b[i] = f2bf(w1[i]);
    if (i < N_CLS * N_HID) w2b[i] = f2bf(w2[i]);
}

// ---------------- fused fc1 -> BN -> ReLU -> fc2, MFMA ----------------
__global__ void __launch_bounds__(256) mlp_k(const short* __restrict__ ftb,
                                             const short* __restrict__ w1b,
                                             const float* __restrict__ b1,
                                             const float* __restrict__ scale,
                                             const float* __restrict__ shift,
                                             const short* __restrict__ w2b,
                                             const float* __restrict__ b2,
                                             float* __restrict__ out) {
    __shared__ short sA[128][136];
    __shared__ short sW1[64][136];
    __shared__ short sH[128][72];
    __shared__ short sW2[64][72];

    int tid = threadIdx.x;
    int w   = tid >> 6;
    int l   = tid & 63;
    int q   = l >> 4;
    int r16 = l & 15;
    int row0 = blockIdx.x * 128;

    for (int i = tid; i < 128 * 16; i += 256) {
        int r = i >> 4, g = i & 15;
        int gr = row0 + r;
        int4 v = {0, 0, 0, 0};
        if (gr < N_NODES) v = *(const int4*)(ftb + (size_t)gr * 128 + g * 8);
        *(int4*)&sA[r][g * 8] = v;
    }

    floatx4 oacc[2][4];
#pragma unroll
    for (int rt = 0; rt < 2; rt++)
#pragma unroll
        for (int tc = 0; tc < 4; tc++) oacc[rt][tc] = (floatx4){0.f, 0.f, 0.f, 0.f};

    for (int jc = 0; jc < 8; jc++) {
        int j0 = jc * 64;
        __syncthreads();
        for (int i = tid; i < 64 * 16; i += 256) {
            int j = i >> 4, k8 = i & 15;
            *(int4*)&sW1[j][k8 * 8] = *(const int4*)&w1b[(size_t)(j0 + j) * IN_F + k8 * 8];
        }
        for (int i = tid; i < 64 * 8; i += 256) {
            int c = i >> 3, k8 = i & 7;
            *(int4*)&sW2[c][k8 * 8] = *(const int4*)&w2b[(size_t)c * N_HID + j0 + k8 * 8];
        }
        __syncthreads();

        floatx4 hacc[2][4];
#pragma unroll
        for (int rt = 0; rt < 2; rt++)
#pragma unroll
            for (int tn = 0; tn < 4; tn++) hacc[rt][tn] = (floatx4){0.f, 0.f, 0.f, 0.f};
#pragma unroll
        for (int ks = 0; ks < 4; ks++) {
            short8 a0 = *(const short8*)&sA[w * 32 + r16][ks * 32 + q * 8];
            short8 a1 = *(const short8*)&sA[w * 32 + 16 + r16][ks * 32 + q * 8];
#pragma unroll
            for (int tn = 0; tn < 4; tn++) {
                short8 b = *(const short8*)&sW1[tn * 16 + r16][ks * 32 + q * 8];
                hacc[0][tn] = __builtin_amdgcn_mfma_f32_16x16x32_bf16(a0, b, hacc[0][tn], 0, 0, 0);
                hacc[1][tn] = __builtin_amdgcn_mfma_f32_16x16x32_bf16(a1, b, hacc[1][tn], 0, 0, 0);
            }
        }
#pragma unroll
        for (int tn = 0; tn < 4; tn++) {
            int col = j0 + tn * 16 + r16;
            float sc = scale[col], sh = shift[col], bb = b1[col];
#pragma unroll
            for (int rt = 0; rt < 2; rt++)
#pragma unroll
                for (int i = 0; i < 4; i++) {
                    float v = (hacc[rt][tn][i] + bb) * sc + sh;
                    sH[w * 32 + rt * 16 + q * 4 + i][tn * 16 + r16] = f2bf(fmaxf(v, 0.f));
                }
        }
        __syncthreads();
#pragma unroll
        for (int ks = 0; ks < 2; ks++) {
            short8 a0 = *(const short8*)&sH[w * 32 + r16][ks * 32 + q * 8];
            short8 a1 = *(const short8*)&sH[w * 32 + 16 + r16][ks * 32 + q * 8];
#pragma unroll
            for (int tc = 0; tc < 4; tc++) {
                short8 b = *(const short8*)&sW2[tc * 16 + r16][ks * 32 + q * 8];
                oacc[0][tc] = __builtin_amdgcn_mfma_f32_16x16x32_bf16(a0, b, oacc[0][tc], 0, 0, 0);
                oacc[1][tc] = __builtin_amdgcn_mfma_f32_16x16x32_bf16(a1, b, oacc[1][tc], 0, 0, 0);
            }
        }
    }

#pragma unroll
    for (int rt = 0; rt < 2; rt++)
#pragma unroll
        for (int tc = 0; tc < 4; tc++) {
            int col = tc * 16 + r16;
            float bb = b2[col];
#pragma unroll
            for (int i = 0; i < 4; i++) {
                int r = row0 + w * 32 + rt * 16 + q * 4 + i;
                if (r < N_NODES) out[(size_t)r * N_CLS + col] = oacc[rt][tc][i] + bb;
            }
        }
}

extern "C" void kernel_launch(void* const* d_in, const int* in_sizes, int n_in,
                              void* d_out, int out_size, void* d_ws, size_t ws_size,
                              hipStream_t stream) {
    const float* feat  = (const float*)d_in[0];
    const int*   src   = (const int*)d_in[1];
    const int*   dst   = (const int*)d_in[2];
    const float* gnorm = (const float*)d_in[3];
    const float* fc1w  = (const float*)d_in[4];
    const float* fc1b  = (const float*)d_in[5];
    const float* gam   = (const float*)d_in[6];
    const float* bet   = (const float*)d_in[7];
    const float* fc2w  = (const float*)d_in[8];
    const float* fc2b  = (const float*)d_in[9];
    float* out = (float*)d_out;

    char* ws = (char*)d_ws;
    const size_t FTB_BYTES = (size_t)N_NODES * IN_F * 2;   // 25.6 MB
    size_t off = 0;
    short* bufA   = (short*)(ws + off); off += FTB_BYTES;  // featb
    short* bufB   = (short*)(ws + off); off += FTB_BYTES;  // ft1b; ft3b aliases after hop2
    short* bufC   = (short*)(ws + off); off += FTB_BYTES;  // ft2b
    int*   indptr = (int*)(ws + off);   off += 460800;     // up to 114689 ints
    int*   cursor = (int*)(ws + off);   off += SCAN_PAD * 4;   // 458752 B, zeroed
    unsigned* sedge = (unsigned*)(ws + off); off += (size_t)N_EDGES * 4;  // packed edges
    float* G      = (float*)(ws + off); off += 128 * 128 * 4;
    float* colsum = (float*)(ws + off); off += 512;
    float* scale  = (float*)(ws + off); off += 2048;
    float* shift  = (float*)(ws + off); off += 2048;
    short* w1b    = (short*)(ws + off); off += (size_t)N_HID * IN_F * 2;
    short* w2b    = (short*)(ws + off); off += (size_t)N_CLS * N_HID * 2;
    // Gpart: 391*64KB = 25,624,576 B — dedicated region (round-5 lesson:
    // it does NOT fit in a 25,600,000 B bf16 ft buffer).
    float* Gpart  = (float*)(ws + off); off += (size_t)NB_GRAM * 16384 * 4;
    short* featb  = bufA;
    short* ft1b   = bufB;
    short* ft2b   = bufC;
    short* ft3b   = bufB;               // reuse (ft1b dead after hop2)
    (void)ws_size; (void)in_sizes; (void)n_in; (void)out_size;

    hipMemsetAsync(cursor, 0, SCAN_PAD * 4, stream);
    hipMemsetAsync(colsum, 0, 512, stream);

    cvtf_k<<<12500, 256, 0, stream>>>((const float4*)feat, featb);
    cvtw_k<<<(N_HID * IN_F + 255) / 256, 256, 0, stream>>>(fc1w, fc2w, w1b, w2b);

    // CSR build
    count_k<<<N_EDGES / 256, 256, 0, stream>>>(dst, cursor);
    scan_k<<<1, 1024, 0, stream>>>(cursor, indptr);
    scatter_k<<<N_EDGES / 256, 256, 0, stream>>>(src, dst, gnorm, cursor, sedge);

    // 3 bf16 propagation hops: featb -> ft1b -> ft2b -> ft3b
    hopb_k<<<(N_NODES + 3) / 4, 256, 0, stream>>>(featb, ft1b, indptr, sedge);
    hopb_k<<<(N_NODES + 3) / 4, 256, 0, stream>>>(ft1b, ft2b, indptr, sedge);
    hopb_k<<<(N_NODES + 3) / 4, 256, 0, stream>>>(ft2b, ft3b, indptr, sedge);

    // BN stats via MFMA Gram (split-K partials + reduction)
    gram_k<<<NB_GRAM, 256, 0, stream>>>(ft3b, Gpart, colsum);
    reduce_k<<<64, 256, 0, stream>>>(Gpart, G);
    bnstat_k<<<N_HID, 128, 0, stream>>>(G, colsum, fc1w, fc1b, gam, bet, scale, shift);

    // fused MFMA MLP
    mlp_k<<<(N_NODES + 127) / 128, 256, 0, stream>>>(ft3b, w1b, fc1b, scale, shift,
                                                     w2b, fc2b, out);
}